// Round 1
// baseline (1187.037 us; speedup 1.0000x reference)
//
#include <hip/hip_runtime.h>
#include <cstddef>

#define NB 8
#define NC 256
#define NH_ 64
#define NW_ 64
#define NQ 4096
#define NHEADS 8
#define NPTS 4
#define NCOUT 320

// ---------------- PE table: LoFTR sinusoidal, [C][H*W] ----------------
__global__ void pe_kernel(float* __restrict__ pe) {
  int idx = blockIdx.x * 256 + threadIdx.x;
  if (idx >= NC * NQ) return;
  int c = idx >> 12;
  int hw = idx & 4095;
  int h = hw >> 6, w = hw & 63;
  int k = c >> 2, m = c & 3;
  float dv = expf((float)(2 * k) * (-9.210340371976184f / 128.0f)); // -ln(1e4)/128
  float arg = ((m < 2) ? (float)w : (float)h) * dv;
  pe[idx] = ((m & 1) == 0) ? sinf(arg) : cosf(arg);
}

// ---------------- GEMM variant A: out[b][m][q] = sum_k W[m][k]*X[b][k][q] + bias[m]
__global__ __launch_bounds__(256) void gemm_wx(
    const float* __restrict__ W, const float* __restrict__ X,
    const float* __restrict__ bias, float* __restrict__ out,
    int M, int K) {
  const int t = threadIdx.x;
  const int b = blockIdx.z;
  const int m0 = blockIdx.y * 64, n0 = blockIdx.x * 64;
  X += (size_t)b * K * NQ;
  out += (size_t)b * M * NQ;
  __shared__ float As[16][68];
  __shared__ float Bs[16][68];
  float acc[4][4] = {};
  const int tx = t & 15, ty = t >> 4;
  const int arow = t >> 2, akq = (t & 3) * 4;
  const int bk = t >> 4, bnq = (t & 15) * 4;
  for (int k0 = 0; k0 < K; k0 += 16) {
    float4 av = *reinterpret_cast<const float4*>(W + (size_t)(m0 + arow) * K + k0 + akq);
    As[akq + 0][arow] = av.x; As[akq + 1][arow] = av.y;
    As[akq + 2][arow] = av.z; As[akq + 3][arow] = av.w;
    float4 bv = *reinterpret_cast<const float4*>(X + (size_t)(k0 + bk) * NQ + n0 + bnq);
    *reinterpret_cast<float4*>(&Bs[bk][bnq]) = bv;
    __syncthreads();
#pragma unroll
    for (int kk = 0; kk < 16; ++kk) {
      float4 a = *reinterpret_cast<const float4*>(&As[kk][ty * 4]);
      float4 bq = *reinterpret_cast<const float4*>(&Bs[kk][tx * 4]);
      acc[0][0] += a.x * bq.x; acc[0][1] += a.x * bq.y; acc[0][2] += a.x * bq.z; acc[0][3] += a.x * bq.w;
      acc[1][0] += a.y * bq.x; acc[1][1] += a.y * bq.y; acc[1][2] += a.y * bq.z; acc[1][3] += a.y * bq.w;
      acc[2][0] += a.z * bq.x; acc[2][1] += a.z * bq.y; acc[2][2] += a.z * bq.z; acc[2][3] += a.z * bq.w;
      acc[3][0] += a.w * bq.x; acc[3][1] += a.w * bq.y; acc[3][2] += a.w * bq.z; acc[3][3] += a.w * bq.w;
    }
    __syncthreads();
  }
#pragma unroll
  for (int i = 0; i < 4; ++i) {
    int m = m0 + ty * 4 + i;
    float bsv = bias[m];
#pragma unroll
    for (int j = 0; j < 4; ++j)
      out[(size_t)m * NQ + n0 + tx * 4 + j] = acc[i][j] + bsv;
  }
}

// ------------- GEMM variant B: out[b][q][o] = sum_k (X[b][k][q]+s*PE[k][q])*W[k][o] + bias[o]
__global__ __launch_bounds__(256) void gemm_xtw(
    const float* __restrict__ X, const float* __restrict__ PEp, float pescale,
    const float* __restrict__ W, const float* __restrict__ bias,
    float* __restrict__ out, int O) {
  const int K = NC;
  const int t = threadIdx.x;
  const int b = blockIdx.z;
  const int q0 = blockIdx.y * 64, o0 = blockIdx.x * 64;
  X += (size_t)b * K * NQ;
  out += (size_t)b * NQ * O;
  __shared__ float As[16][68]; // [k][q]
  __shared__ float Bs[16][68]; // [k][o]
  float acc[4][4] = {};
  const int tx = t & 15, ty = t >> 4;
  const int lk = t >> 4, lq = (t & 15) * 4;
  for (int k0 = 0; k0 < K; k0 += 16) {
    size_t xoff = (size_t)(k0 + lk) * NQ + q0 + lq;
    float4 av = *reinterpret_cast<const float4*>(X + xoff);
    if (PEp) {
      float4 pv = *reinterpret_cast<const float4*>(PEp + xoff);
      av.x += pescale * pv.x; av.y += pescale * pv.y;
      av.z += pescale * pv.z; av.w += pescale * pv.w;
    }
    *reinterpret_cast<float4*>(&As[lk][lq]) = av;
    float4 bv = make_float4(0.f, 0.f, 0.f, 0.f);
    if (o0 + lq < O)
      bv = *reinterpret_cast<const float4*>(W + (size_t)(k0 + lk) * O + o0 + lq);
    *reinterpret_cast<float4*>(&Bs[lk][lq]) = bv;
    __syncthreads();
#pragma unroll
    for (int kk = 0; kk < 16; ++kk) {
      float4 a = *reinterpret_cast<const float4*>(&As[kk][ty * 4]);
      float4 bq = *reinterpret_cast<const float4*>(&Bs[kk][tx * 4]);
      acc[0][0] += a.x * bq.x; acc[0][1] += a.x * bq.y; acc[0][2] += a.x * bq.z; acc[0][3] += a.x * bq.w;
      acc[1][0] += a.y * bq.x; acc[1][1] += a.y * bq.y; acc[1][2] += a.y * bq.z; acc[1][3] += a.y * bq.w;
      acc[2][0] += a.z * bq.x; acc[2][1] += a.z * bq.y; acc[2][2] += a.z * bq.z; acc[2][3] += a.z * bq.w;
      acc[3][0] += a.w * bq.x; acc[3][1] += a.w * bq.y; acc[3][2] += a.w * bq.z; acc[3][3] += a.w * bq.w;
    }
    __syncthreads();
  }
#pragma unroll
  for (int i = 0; i < 4; ++i) {
    int q = q0 + ty * 4 + i;
#pragma unroll
    for (int j = 0; j < 4; ++j) {
      int o = o0 + tx * 4 + j;
      if (o < O) out[(size_t)q * O + o] = acc[i][j] + bias[o];
    }
  }
}

// ------------- GEMM variant C (output proj + residual + optional blend):
// out[b][c][q] = sum_k op_w[k][c]*Y[b][q][k] + op_b[c] + 2*(G[b][c][q] + s*PE[c][q])
// if other != null: out = a*other + (1-a)*out
__global__ __launch_bounds__(256) void gemm_op(
    const float* __restrict__ Wop, const float* __restrict__ Y,
    const float* __restrict__ bias, const float* __restrict__ G,
    const float* __restrict__ PEp, float pescale,
    const float* __restrict__ other, const float* __restrict__ afin,
    float* __restrict__ out) {
  const int K = NC;
  const int t = threadIdx.x;
  const int b = blockIdx.z;
  const int c0 = blockIdx.y * 64, q0 = blockIdx.x * 64;
  Y += (size_t)b * NQ * NC;
  const size_t boff = (size_t)b * NC * NQ;
  __shared__ float As[16][68]; // [k][c]
  __shared__ float Bs[16][68]; // [k][q]
  float acc[4][4] = {};
  const int tx = t & 15, ty = t >> 4;
  const int lk = t >> 4, lc = (t & 15) * 4;
  const int yq = t >> 2, ykq = (t & 3) * 4;
  for (int k0 = 0; k0 < K; k0 += 16) {
    float4 av = *reinterpret_cast<const float4*>(Wop + (size_t)(k0 + lk) * NC + c0 + lc);
    *reinterpret_cast<float4*>(&As[lk][lc]) = av;
    float4 bv = *reinterpret_cast<const float4*>(Y + (size_t)(q0 + yq) * NC + k0 + ykq);
    Bs[ykq + 0][yq] = bv.x; Bs[ykq + 1][yq] = bv.y;
    Bs[ykq + 2][yq] = bv.z; Bs[ykq + 3][yq] = bv.w;
    __syncthreads();
#pragma unroll
    for (int kk = 0; kk < 16; ++kk) {
      float4 a = *reinterpret_cast<const float4*>(&As[kk][ty * 4]);
      float4 bq = *reinterpret_cast<const float4*>(&Bs[kk][tx * 4]);
      acc[0][0] += a.x * bq.x; acc[0][1] += a.x * bq.y; acc[0][2] += a.x * bq.z; acc[0][3] += a.x * bq.w;
      acc[1][0] += a.y * bq.x; acc[1][1] += a.y * bq.y; acc[1][2] += a.y * bq.z; acc[1][3] += a.y * bq.w;
      acc[2][0] += a.z * bq.x; acc[2][1] += a.z * bq.y; acc[2][2] += a.z * bq.z; acc[2][3] += a.z * bq.w;
      acc[3][0] += a.w * bq.x; acc[3][1] += a.w * bq.y; acc[3][2] += a.w * bq.z; acc[3][3] += a.w * bq.w;
    }
    __syncthreads();
  }
  float ab = 0.f;
  if (other) ab = afin[b];
#pragma unroll
  for (int i = 0; i < 4; ++i) {
    int c = c0 + ty * 4 + i;
    float bsv = bias[c];
#pragma unroll
    for (int j = 0; j < 4; ++j) {
      int q = q0 + tx * 4 + j;
      size_t gi = (size_t)c * NQ + q;
      float r = acc[i][j] + bsv + 2.0f * (G[boff + gi] + pescale * PEp[gi]);
      if (other) r = ab * other[boff + gi] + (1.0f - ab) * r;
      out[boff + gi] = r;
    }
  }
}

// ------------- alpha gate: per-q sigmoid(relu(g_row@w1+b1)@w2+b2), block partial sums
__global__ __launch_bounds__(256) void alpha_kernel(
    const float* __restrict__ G, const float* __restrict__ w1,
    const float* __restrict__ b1, const float* __restrict__ w2,
    const float* __restrict__ b2, float* __restrict__ partial) {
  int b = blockIdx.y;
  int wave = threadIdx.x >> 6, lane = threadIdx.x & 63;
  int q = blockIdx.x * 4 + wave;
  const float* grow = G + (size_t)b * NC * NQ + q;
  float h = 0.f;
#pragma unroll 8
  for (int k = 0; k < NC; ++k) h = fmaf(grow[(size_t)k * NQ], w1[k * 64 + lane], h);
  h = fmaxf(h + b1[lane], 0.f) * w2[lane];
#pragma unroll
  for (int off = 32; off; off >>= 1) h += __shfl_xor(h, off);
  __shared__ float sm[4];
  if (lane == 0) sm[wave] = 1.f / (1.f + expf(-(h + b2[0])));
  __syncthreads();
  if (threadIdx.x == 0)
    partial[(size_t)b * 1024 + blockIdx.x] = sm[0] + sm[1] + sm[2] + sm[3];
}

__global__ __launch_bounds__(256) void alpha_finalize(
    const float* __restrict__ partial, float* __restrict__ afinal,
    float* __restrict__ out_a) {
  int b = blockIdx.x;
  __shared__ float sm[256];
  float s = 0.f;
  for (int i = threadIdx.x; i < 1024; i += 256) s += partial[(size_t)b * 1024 + i];
  sm[threadIdx.x] = s;
  __syncthreads();
  for (int st = 128; st; st >>= 1) {
    if (threadIdx.x < st) sm[threadIdx.x] += sm[threadIdx.x + st];
    __syncthreads();
  }
  if (threadIdx.x == 0) {
    float a = sm[0] * (1.f / 4096.f);
    afinal[b] = a;
    out_a[b] = a;
  }
}

// ------------- deformable sampling: oattn[b][q][h*32+hd]
__global__ __launch_bounds__(256) void sample_kernel(
    const float* __restrict__ vproj, const float* __restrict__ offb,
    const float* __restrict__ awb, float* __restrict__ oattn) {
  int b = blockIdx.y, q = blockIdx.x;
  int t = threadIdx.x;
  int head = t >> 5, hd = t & 31;
  const float* off = offb + ((size_t)b * NQ + q) * 64 + head * 8;
  const float* awl = awb + ((size_t)b * NQ + q) * 32 + head * 4;
  float l0 = awl[0], l1 = awl[1], l2 = awl[2], l3 = awl[3];
  float mx = fmaxf(fmaxf(l0, l1), fmaxf(l2, l3));
  float e0 = expf(l0 - mx), e1 = expf(l1 - mx), e2 = expf(l2 - mx), e3 = expf(l3 - mx);
  float inv = 1.f / (e0 + e1 + e2 + e3);
  float aw[4] = {e0 * inv, e1 * inv, e2 * inv, e3 * inv};
  float rpx = (float)(q & 63) * (1.f / 63.f);
  float rpy = (float)(q >> 6) * (1.f / 63.f);
  const float* vb = vproj + (size_t)b * NQ * NC + head * 32 + hd;
  float acc = 0.f;
#pragma unroll
  for (int p = 0; p < 4; ++p) {
    float px = (rpx + off[p * 2 + 0] * (1.f / 64.f)) * 64.f - 0.5f;
    float py = (rpy + off[p * 2 + 1] * (1.f / 64.f)) * 64.f - 0.5f;
    float fx = floorf(px), fy = floorf(py);
    int x0 = (int)fx, y0 = (int)fy;
    float wx = px - fx, wy = py - fy;
    float s = 0.f;
#pragma unroll
    for (int dy = 0; dy < 2; ++dy) {
#pragma unroll
      for (int dx = 0; dx < 2; ++dx) {
        int xi = x0 + dx, yi = y0 + dy;
        if (xi >= 0 && xi < NW_ && yi >= 0 && yi < NH_) {
          float wgt = (dx ? wx : 1.f - wx) * (dy ? wy : 1.f - wy);
          s += wgt * vb[(size_t)(yi * NW_ + xi) * NC];
        }
      }
    }
    acc += aw[p] * s;
  }
  oattn[((size_t)b * NQ + q) * NC + t] = acc;
}

extern "C" void kernel_launch(void* const* d_in, const int* in_sizes, int n_in,
                              void* d_out, int out_size, void* d_ws, size_t ws_size,
                              hipStream_t stream) {
  const float* ground = (const float*)d_in[0];
  const float* sat = (const float*)d_in[1];
  const float* osm = (const float*)d_in[2];
  const float* gc_w = (const float*)d_in[3];
  const float* gc_b = (const float*)d_in[4];
  const float* sc_w = (const float*)d_in[5];
  const float* sc_b = (const float*)d_in[6];
  const float* up_w = (const float*)d_in[7];
  const float* up_b = (const float*)d_in[8];
  const float* a_w1 = (const float*)d_in[9];
  const float* a_b1 = (const float*)d_in[10];
  const float* a_w2 = (const float*)d_in[11];
  const float* a_b2 = (const float*)d_in[12];
  const float* vp_w[2] = {(const float*)d_in[13], (const float*)d_in[21]};
  const float* vp_b[2] = {(const float*)d_in[14], (const float*)d_in[22]};
  const float* so_w[2] = {(const float*)d_in[15], (const float*)d_in[23]};
  const float* so_b[2] = {(const float*)d_in[16], (const float*)d_in[24]};
  const float* aw_w[2] = {(const float*)d_in[17], (const float*)d_in[25]};
  const float* aw_b[2] = {(const float*)d_in[18], (const float*)d_in[26]};
  const float* op_w[2] = {(const float*)d_in[19], (const float*)d_in[27]};
  const float* op_b[2] = {(const float*)d_in[20], (const float*)d_in[28]};

  float* ws = (float*)d_ws;
  float* PEb = ws;                      // 1,048,576
  float* G = PEb + 1048576;             // 8,388,608
  float* VBUF = G + 8388608;            // 8,388,608 (value conv, then oattn)
  float* PBUF = VBUF + 8388608;         // 8,388,608 (vproj, then fused)
  float* OFFB = PBUF + 8388608;         // 2,097,152
  float* AWB = OFFB + 2097152;          // 1,048,576
  float* OUT1 = AWB + 1048576;          // 8,388,608 (sat_out, then fused in-place)
  float* PART = OUT1 + 8388608;         // 8,192
  float* AFIN = PART + 8192;            // 8

  float* out = (float*)d_out;
  float* out_a = out + (size_t)NB * NCOUT * NQ;

  dim3 blk(256);

  pe_kernel<<<dim3((NC * NQ + 255) / 256), blk, 0, stream>>>(PEb);
  // g = gc_w x ground
  gemm_wx<<<dim3(64, 4, NB), blk, 0, stream>>>(gc_w, ground, gc_b, G, 256, 1024);
  // alpha
  alpha_kernel<<<dim3(1024, NB), blk, 0, stream>>>(G, a_w1, a_b1, a_w2, a_b2, PART);
  alpha_finalize<<<dim3(NB), blk, 0, stream>>>(PART, AFIN, out_a);

  const float* val_in[2] = {sat, osm};
  for (int br = 0; br < 2; ++br) {
    float pescale = (float)(br + 1); // sat: g+PE ; osm: g+2*PE (in-place torch bug)
    // value conv (NOTE: osm also uses sc_w/sc_b -- source bug kept)
    gemm_wx<<<dim3(64, 4, NB), blk, 0, stream>>>(sc_w, val_in[br], sc_b, VBUF, 256, 320);
    // vproj [B,Q,C]
    gemm_xtw<<<dim3(4, 64, NB), blk, 0, stream>>>(VBUF, nullptr, 0.f, vp_w[br], vp_b[br], PBUF, 256);
    // sampling offsets [B,Q,64] and attention logits [B,Q,32] from qf = g + s*PE
    gemm_xtw<<<dim3(1, 64, NB), blk, 0, stream>>>(G, PEb, pescale, so_w[br], so_b[br], OFFB, 64);
    gemm_xtw<<<dim3(1, 64, NB), blk, 0, stream>>>(G, PEb, pescale, aw_w[br], aw_b[br], AWB, 32);
    // gather + softmax-weighted sum -> oattn (reuses VBUF)
    sample_kernel<<<dim3(NQ, NB), blk, 0, stream>>>(PBUF, OFFB, AWB, VBUF);
    // output proj + 2*(g+s*PE); osm pass blends with sat_out in-place into OUT1
    if (br == 0)
      gemm_op<<<dim3(64, 4, NB), blk, 0, stream>>>(op_w[br], VBUF, op_b[br], G, PEb,
                                                   pescale, nullptr, nullptr, OUT1);
    else
      gemm_op<<<dim3(64, 4, NB), blk, 0, stream>>>(op_w[br], VBUF, op_b[br], G, PEb,
                                                   pescale, OUT1, AFIN, OUT1);
  }
  // final up-conv on fused (OUT1)
  gemm_wx<<<dim3(64, 5, NB), blk, 0, stream>>>(up_w, OUT1, up_b, out, NCOUT, 256);
}

// Round 2
// 499.973 us; speedup vs baseline: 2.3742x; 2.3742x over previous
//
#include <hip/hip_runtime.h>
#include <cstddef>
#include <cstdint>

#define NB 8
#define NQ 4096

typedef __attribute__((ext_vector_type(8))) short bfrag8;
typedef __attribute__((ext_vector_type(4))) float facc4;
typedef __attribute__((ext_vector_type(4))) unsigned short us4;

__device__ __forceinline__ float bf2f(unsigned short u) {
  union { unsigned int i; float f; } v; v.i = ((unsigned int)u) << 16; return v.f;
}
__device__ __forceinline__ unsigned short f2bf(float f) {
  union { float f; unsigned int i; } v; v.f = f;
  unsigned int r = v.i + 0x7FFFu + ((v.i >> 16) & 1u);
  return (unsigned short)(r >> 16);
}
__device__ __forceinline__ void gload16(const void* g, void* l) {
  __builtin_amdgcn_global_load_lds(
      (const __attribute__((address_space(1))) void*)g,
      (__attribute__((address_space(3))) void*)l, 16, 0, 0);
}

// ---------------- tiny weight prep ----------------
__global__ __launch_bounds__(256) void k_cvt(const float* __restrict__ s,
                                             unsigned short* __restrict__ d, int n) {
  int i = blockIdx.x * 256 + threadIdx.x;
  if (i < n) d[i] = f2bf(s[i]);
}
// up_w [320][256] -> [384][256] bf16 zero-padded
__global__ __launch_bounds__(256) void k_wup(const float* __restrict__ s,
                                             unsigned short* __restrict__ d) {
  int i = blockIdx.x * 256 + threadIdx.x; // < 384*256
  int m = i >> 8, k = i & 255;
  d[i] = (m < 320) ? f2bf(s[m * 256 + k]) : 0;
}
// vp_w/op_w [k][o] 256x256 -> [o][k] bf16
__global__ __launch_bounds__(256) void k_wtrans(const float* __restrict__ s,
                                                unsigned short* __restrict__ d) {
  int i = blockIdx.x * 256 + threadIdx.x; // < 65536
  int o = i >> 8, k = i & 255;
  d[i] = f2bf(s[(k << 8) + o]);
}
// so_w [256][64], aw_w [256][32] -> W[128][256] (rows 0-63 soT, 64-95 awT, 96-127 zero) + bias[128]
__global__ __launch_bounds__(256) void k_soaw(const float* __restrict__ so_w,
                                              const float* __restrict__ so_b,
                                              const float* __restrict__ aw_w,
                                              const float* __restrict__ aw_b,
                                              unsigned short* __restrict__ W,
                                              float* __restrict__ Bb) {
  int i = blockIdx.x * 256 + threadIdx.x; // < 32768
  int row = i >> 8, k = i & 255;
  float v = 0.f;
  if (row < 64) v = so_w[k * 64 + row];
  else if (row < 96) v = aw_w[k * 32 + (row - 64)];
  W[i] = f2bf(v);
  if (i < 128) Bb[i] = (i < 64) ? so_b[i] : ((i < 96) ? aw_b[i - 64] : 0.f);
}
__global__ __launch_bounds__(256) void k_bup(const float* __restrict__ s, float* __restrict__ d) {
  int i = blockIdx.x * 256 + threadIdx.x;
  if (i < 384) d[i] = (i < 320) ? s[i] : 0.f;
}

// ---------------- PE table bf16 [Q][256] ----------------
__global__ __launch_bounds__(256) void pe_kernel(unsigned short* __restrict__ pe) {
  int idx = blockIdx.x * 256 + threadIdx.x; // < 4096*256
  int q = idx >> 8, c = idx & 255;
  int h = q >> 6, w = q & 63;
  int k = c >> 2, m = c & 3;
  float dv = expf((float)(2 * k) * (-9.210340371976184f / 128.0f));
  float arg = ((m < 2) ? (float)w : (float)h) * dv;
  pe[idx] = f2bf(((m & 1) == 0) ? sinf(arg) : cosf(arg));
}

// ---------------- transpose-convert: [B][K][4096] f32 -> [B][4096][K] bf16 ----------------
__global__ __launch_bounds__(256) void k_transpose(const float* __restrict__ src,
                                                   unsigned short* __restrict__ dst, int K) {
  int b = blockIdx.z;
  int k0 = blockIdx.y * 32, n0 = blockIdx.x * 32;
  const float* s = src + (size_t)b * K * NQ;
  unsigned short* d = dst + (size_t)b * NQ * K;
  __shared__ float tile[32][33];
  int t = threadIdx.x;
  int r = t >> 3, cg = (t & 7) * 4;
  float4 v = *reinterpret_cast<const float4*>(&s[(size_t)(k0 + r) * NQ + n0 + cg]);
  tile[r][cg + 0] = v.x; tile[r][cg + 1] = v.y; tile[r][cg + 2] = v.z; tile[r][cg + 3] = v.w;
  __syncthreads();
  us4 pk;
  pk[0] = f2bf(tile[cg + 0][r]); pk[1] = f2bf(tile[cg + 1][r]);
  pk[2] = f2bf(tile[cg + 2][r]); pk[3] = f2bf(tile[cg + 3][r]);
  *reinterpret_cast<us4*>(&d[(size_t)(n0 + r) * K + k0 + cg]) = pk;
}

// ---------------- QF1 = G + PE, QF2 = G + 2PE (bf16) ----------------
__global__ __launch_bounds__(256) void k_qf(const unsigned short* __restrict__ G,
                                            const unsigned short* __restrict__ PET,
                                            unsigned short* __restrict__ QF1,
                                            unsigned short* __restrict__ QF2) {
  int b = blockIdx.y;
  size_t idx = ((size_t)blockIdx.x * 256 + threadIdx.x) * 8; // within batch, < 4096*256
  size_t gi = (size_t)b * NQ * 256 + idx;
  bfrag8 g = *reinterpret_cast<const bfrag8*>(&G[gi]);
  bfrag8 p = *reinterpret_cast<const bfrag8*>(&PET[idx]);
  us4 q1a, q1b, q2a, q2b;
#pragma unroll
  for (int j = 0; j < 8; ++j) {
    float gf = bf2f((unsigned short)g[j]);
    float pf = bf2f((unsigned short)p[j]);
    unsigned short r1 = f2bf(gf + pf), r2 = f2bf(gf + 2.f * pf);
    if (j < 4) { q1a[j] = r1; q2a[j] = r2; } else { q1b[j - 4] = r1; q2b[j - 4] = r2; }
  }
  *reinterpret_cast<us4*>(&QF1[gi]) = q1a;
  *reinterpret_cast<us4*>(&QF1[gi + 4]) = q1b;
  *reinterpret_cast<us4*>(&QF2[gi]) = q2a;
  *reinterpret_cast<us4*>(&QF2[gi + 4]) = q2b;
}

// ---------------- bf16 MFMA GEMM ----------------
// W [Mpad][K] bf16, X [B][4096][K] bf16.
// MODE 0: out bf16 [B][N][ldm] = acc + bias
// MODE 1: out bf16 [B][N][256] = acc + bias + 2*res
// MODE 2: out bf16 [B][N][256] = a*other + (1-a)*(acc + bias + 2*res)
// MODE 3: out f32 [B][Mreal][4096] = acc + bias (store masked m < Mreal)
template <int MODE>
__global__ __launch_bounds__(256) void gemm_bf16(
    const unsigned short* __restrict__ W, const unsigned short* __restrict__ X,
    const float* __restrict__ bias, void* __restrict__ outp,
    const unsigned short* __restrict__ res, const unsigned short* __restrict__ other,
    const float* __restrict__ afin, int K, int ldm, int Mreal) {
  __shared__ unsigned short As[8192]; // [128][64]
  __shared__ unsigned short Bs[8192];
  const int t = threadIdx.x;
  const int lane = t & 63, w = t >> 6;
  const int b = blockIdx.z;
  const int n0 = blockIdx.x * 128, m0 = blockIdx.y * 128;
  const unsigned short* Xb = X + (size_t)b * NQ * K;

  const unsigned short* asrc[4];
  const unsigned short* bsrc[4];
  unsigned short* adst[4];
  unsigned short* bdst[4];
#pragma unroll
  for (int i = 0; i < 4; ++i) {
    int cid = i * 256 + t;
    int row = cid >> 3;
    int cc = (cid & 7) ^ (row & 7); // pre-swizzled source chunk
    asrc[i] = W + (size_t)(m0 + row) * K + cc * 8;
    bsrc[i] = Xb + (size_t)(n0 + row) * K + cc * 8;
    adst[i] = &As[i * 2048 + w * 512]; // wave-uniform base; HW adds lane*16B
    bdst[i] = &Bs[i * 2048 + w * 512];
  }

  const int wm = (w >> 1) * 64, wn = (w & 1) * 64;
  const int l15 = lane & 15, l4 = lane >> 4;
  facc4 acc[4][4];
#pragma unroll
  for (int i = 0; i < 4; ++i)
#pragma unroll
    for (int j = 0; j < 4; ++j) acc[i][j] = facc4{0.f, 0.f, 0.f, 0.f};

  for (int k0 = 0; k0 < K; k0 += 64) {
    if (k0) __syncthreads();
#pragma unroll
    for (int i = 0; i < 4; ++i) {
      gload16(asrc[i], adst[i]);
      gload16(bsrc[i], bdst[i]);
      asrc[i] += 64; bsrc[i] += 64;
    }
    __syncthreads();
#pragma unroll
    for (int kk = 0; kk < 2; ++kk) {
      bfrag8 af[4], bf[4];
#pragma unroll
      for (int mi = 0; mi < 4; ++mi) {
        int row = wm + mi * 16 + l15;
        af[mi] = *reinterpret_cast<const bfrag8*>(
            &As[row * 64 + (((kk * 4 + l4) ^ (row & 7)) * 8)]);
      }
#pragma unroll
      for (int ni = 0; ni < 4; ++ni) {
        int row = wn + ni * 16 + l15;
        bf[ni] = *reinterpret_cast<const bfrag8*>(
            &Bs[row * 64 + (((kk * 4 + l4) ^ (row & 7)) * 8)]);
      }
#pragma unroll
      for (int mi = 0; mi < 4; ++mi)
#pragma unroll
        for (int ni = 0; ni < 4; ++ni)
          acc[mi][ni] = __builtin_amdgcn_mfma_f32_16x16x32_bf16(af[mi], bf[ni], acc[mi][ni], 0, 0, 0);
    }
  }

  const size_t bq = (size_t)b * NQ;
#pragma unroll
  for (int mi = 0; mi < 4; ++mi) {
#pragma unroll
    for (int ni = 0; ni < 4; ++ni) {
      int m = m0 + wm + mi * 16 + l4 * 4;
      int n = n0 + wn + ni * 16 + l15;
      facc4 v = acc[mi][ni];
      if constexpr (MODE == 3) {
        float* o32 = (float*)outp;
#pragma unroll
        for (int r = 0; r < 4; ++r)
          if (m + r < Mreal)
            o32[((size_t)b * Mreal + (m + r)) * NQ + n] = v[r] + bias[m + r];
      } else {
        unsigned short* o16 = (unsigned short*)outp;
        float4 bv = *reinterpret_cast<const float4*>(&bias[m]);
        float rv[4] = {v[0] + bv.x, v[1] + bv.y, v[2] + bv.z, v[3] + bv.w};
        if constexpr (MODE >= 1) {
          us4 qv = *reinterpret_cast<const us4*>(&res[(bq + n) * 256 + m]);
#pragma unroll
          for (int r = 0; r < 4; ++r) rv[r] += 2.f * bf2f(qv[r]);
        }
        if constexpr (MODE == 2) {
          float a = afin[b];
          us4 ov = *reinterpret_cast<const us4*>(&other[(bq + n) * 256 + m]);
#pragma unroll
          for (int r = 0; r < 4; ++r) rv[r] = a * bf2f(ov[r]) + (1.f - a) * rv[r];
        }
        us4 pk;
#pragma unroll
        for (int r = 0; r < 4; ++r) pk[r] = f2bf(rv[r]);
        *reinterpret_cast<us4*>(&o16[(bq + n) * ldm + m]) = pk;
      }
    }
  }
}

// ---------------- alpha gate ----------------
__global__ __launch_bounds__(256) void k_alpha(const unsigned short* __restrict__ G,
                                               const float* __restrict__ w1,
                                               const float* __restrict__ b1,
                                               const float* __restrict__ w2,
                                               const float* __restrict__ b2,
                                               float* __restrict__ partial) {
  int b = blockIdx.y;
  int qbase = blockIdx.x * 16;
  __shared__ float gs[16][256];
  __shared__ float wsum[4];
  int t = threadIdx.x;
  const unsigned short* gp = G + ((size_t)b * NQ + qbase) * 256;
#pragma unroll
  for (int i = t; i < 512; i += 256) {
    bfrag8 v = *reinterpret_cast<const bfrag8*>(&gp[i * 8]);
    int row = i >> 5, col = (i & 31) * 8;
#pragma unroll
    for (int j = 0; j < 8; ++j) gs[row][col + j] = bf2f((unsigned short)v[j]);
  }
  __syncthreads();
  int wv = t >> 6, lane = t & 63;
  float a0 = 0.f, a1 = 0.f, a2 = 0.f, a3 = 0.f;
  const float* g0 = gs[wv * 4 + 0];
  const float* g1 = gs[wv * 4 + 1];
  const float* g2 = gs[wv * 4 + 2];
  const float* g3 = gs[wv * 4 + 3];
#pragma unroll 4
  for (int k = 0; k < 256; ++k) {
    float wk = w1[k * 64 + lane];
    a0 = fmaf(g0[k], wk, a0); a1 = fmaf(g1[k], wk, a1);
    a2 = fmaf(g2[k], wk, a2); a3 = fmaf(g3[k], wk, a3);
  }
  float b1l = b1[lane], w2l = w2[lane];
  a0 = fmaxf(a0 + b1l, 0.f) * w2l; a1 = fmaxf(a1 + b1l, 0.f) * w2l;
  a2 = fmaxf(a2 + b1l, 0.f) * w2l; a3 = fmaxf(a3 + b1l, 0.f) * w2l;
#pragma unroll
  for (int off = 32; off; off >>= 1) {
    a0 += __shfl_xor(a0, off); a1 += __shfl_xor(a1, off);
    a2 += __shfl_xor(a2, off); a3 += __shfl_xor(a3, off);
  }
  if (lane == 0) {
    float bb = b2[0];
    float s = 1.f / (1.f + expf(-(a0 + bb))) + 1.f / (1.f + expf(-(a1 + bb))) +
              1.f / (1.f + expf(-(a2 + bb))) + 1.f / (1.f + expf(-(a3 + bb)));
    wsum[wv] = s;
  }
  __syncthreads();
  if (t == 0) partial[(size_t)b * 256 + blockIdx.x] = wsum[0] + wsum[1] + wsum[2] + wsum[3];
}

__global__ __launch_bounds__(256) void k_alpha_fin(const float* __restrict__ partial,
                                                   float* __restrict__ afin,
                                                   float* __restrict__ out_a) {
  int b = blockIdx.x;
  __shared__ float sm[256];
  sm[threadIdx.x] = partial[(size_t)b * 256 + threadIdx.x];
  __syncthreads();
  for (int st = 128; st; st >>= 1) {
    if (threadIdx.x < st) sm[threadIdx.x] += sm[threadIdx.x + st];
    __syncthreads();
  }
  if (threadIdx.x == 0) {
    float a = sm[0] * (1.f / 4096.f);
    afin[b] = a;
    out_a[b] = a;
  }
}

// ---------------- deformable bilinear sampling (bf16) ----------------
__global__ __launch_bounds__(256) void k_sample(const unsigned short* __restrict__ VP,
                                                const unsigned short* __restrict__ SW,
                                                unsigned short* __restrict__ OATT) {
  int b = blockIdx.y, q = blockIdx.x;
  int t = threadIdx.x, head = t >> 5, hd = t & 31;
  const unsigned short* sw = SW + ((size_t)b * NQ + q) * 128;
  float l0 = bf2f(sw[64 + head * 4 + 0]);
  float l1 = bf2f(sw[64 + head * 4 + 1]);
  float l2 = bf2f(sw[64 + head * 4 + 2]);
  float l3 = bf2f(sw[64 + head * 4 + 3]);
  float mx = fmaxf(fmaxf(l0, l1), fmaxf(l2, l3));
  float e0 = expf(l0 - mx), e1 = expf(l1 - mx), e2 = expf(l2 - mx), e3 = expf(l3 - mx);
  float inv = 1.f / (e0 + e1 + e2 + e3);
  float aw[4] = {e0 * inv, e1 * inv, e2 * inv, e3 * inv};
  float rpx = (float)(q & 63) * (64.f / 63.f) - 0.5f;
  float rpy = (float)(q >> 6) * (64.f / 63.f) - 0.5f;
  const unsigned short* vb = VP + (size_t)b * NQ * 256 + head * 32 + hd;
  float acc = 0.f;
#pragma unroll
  for (int p = 0; p < 4; ++p) {
    float px = rpx + bf2f(sw[head * 8 + p * 2 + 0]);
    float py = rpy + bf2f(sw[head * 8 + p * 2 + 1]);
    float fx = floorf(px), fy = floorf(py);
    int x0 = (int)fx, y0 = (int)fy;
    float wx = px - fx, wy = py - fy;
    float s = 0.f;
#pragma unroll
    for (int dy = 0; dy < 2; ++dy) {
#pragma unroll
      for (int dx = 0; dx < 2; ++dx) {
        int xi = x0 + dx, yi = y0 + dy;
        if (xi >= 0 && xi < 64 && yi >= 0 && yi < 64) {
          float wgt = (dx ? wx : 1.f - wx) * (dy ? wy : 1.f - wy);
          s += wgt * bf2f(vb[(size_t)(yi * 64 + xi) * 256]);
        }
      }
    }
    acc += aw[p] * s;
  }
  OATT[((size_t)b * NQ + q) * 256 + t] = f2bf(acc);
}

extern "C" void kernel_launch(void* const* d_in, const int* in_sizes, int n_in,
                              void* d_out, int out_size, void* d_ws, size_t ws_size,
                              hipStream_t stream) {
  const float* ground = (const float*)d_in[0];
  const float* sat = (const float*)d_in[1];
  const float* osm = (const float*)d_in[2];
  const float* gc_w = (const float*)d_in[3];
  const float* gc_b = (const float*)d_in[4];
  const float* sc_w = (const float*)d_in[5];
  const float* sc_b = (const float*)d_in[6];
  const float* up_w = (const float*)d_in[7];
  const float* up_b = (const float*)d_in[8];
  const float* a_w1 = (const float*)d_in[9];
  const float* a_b1 = (const float*)d_in[10];
  const float* a_w2 = (const float*)d_in[11];
  const float* a_b2 = (const float*)d_in[12];
  const float* vp_w[2] = {(const float*)d_in[13], (const float*)d_in[21]};
  const float* vp_b[2] = {(const float*)d_in[14], (const float*)d_in[22]};
  const float* so_w[2] = {(const float*)d_in[15], (const float*)d_in[23]};
  const float* so_b[2] = {(const float*)d_in[16], (const float*)d_in[24]};
  const float* aw_w[2] = {(const float*)d_in[17], (const float*)d_in[25]};
  const float* aw_b[2] = {(const float*)d_in[18], (const float*)d_in[26]};
  const float* op_w[2] = {(const float*)d_in[19], (const float*)d_in[27]};
  const float* op_b[2] = {(const float*)d_in[20], (const float*)d_in[28]};

  char* wsb = (char*)d_ws;
  const size_t MBy = 1 << 20;
  unsigned short* PET  = (unsigned short*)(wsb);
  unsigned short* WG   = (unsigned short*)(wsb + 2 * MBy);
  unsigned short* WS   = (unsigned short*)(wsb + (size_t)(2.5 * MBy));
  unsigned short* WUP  = (unsigned short*)(wsb + (size_t)(2.75 * MBy));
  unsigned short* VPT0 = (unsigned short*)(wsb + 3 * MBy);
  unsigned short* VPT1 = (unsigned short*)(wsb + 3 * MBy + 131072);
  unsigned short* OPT0 = (unsigned short*)(wsb + 3 * MBy + 262144);
  unsigned short* OPT1 = (unsigned short*)(wsb + 3 * MBy + 393216);
  unsigned short* SOW0 = (unsigned short*)(wsb + 3 * MBy + 524288);
  unsigned short* SOW1 = (unsigned short*)(wsb + 3 * MBy + 589824);
  float* SOB0 = (float*)(wsb + 3 * MBy + 655360);
  float* SOB1 = (float*)(wsb + 3 * MBy + 656384);
  float* BUPP = (float*)(wsb + 3 * MBy + 657408);
  float* PART = (float*)(wsb + 3 * MBy + 786432); // 8KB
  float* AFIN = (float*)(wsb + 3 * MBy + 794624);
  unsigned short* G    = (unsigned short*)(wsb + 4 * MBy);   // 16 MB, later FUSED
  unsigned short* QF1  = (unsigned short*)(wsb + 20 * MBy);  // 16 MB
  unsigned short* QF2  = (unsigned short*)(wsb + 36 * MBy);  // 16 MB
  unsigned short* VB   = (unsigned short*)(wsb + 52 * MBy);  // 16 MB, later OATT
  unsigned short* VP   = (unsigned short*)(wsb + 68 * MBy);  // 16 MB
  unsigned short* XG   = (unsigned short*)(wsb + 84 * MBy);  // 64 MB (dies after gconv)
  unsigned short* XS   = (unsigned short*)(wsb + 84 * MBy);  // 20 MB
  unsigned short* XO   = (unsigned short*)(wsb + 104 * MBy); // 20 MB
  unsigned short* SW   = (unsigned short*)(wsb + 124 * MBy); // 8 MB
  unsigned short* SATO = (unsigned short*)(wsb + 132 * MBy); // 16 MB (ends 148 MB)
  unsigned short* FUSED = G;
  unsigned short* OATT = VB;

  float* out32 = (float*)d_out;
  float* out_a = out32 + (size_t)NB * 320 * NQ;

  dim3 blk(256);
  // ---- prep ----
  k_cvt<<<dim3(1024), blk, 0, stream>>>(gc_w, WG, 262144);
  k_cvt<<<dim3(320), blk, 0, stream>>>(sc_w, WS, 81920);
  k_wup<<<dim3(384), blk, 0, stream>>>(up_w, WUP);
  k_wtrans<<<dim3(256), blk, 0, stream>>>(vp_w[0], VPT0);
  k_wtrans<<<dim3(256), blk, 0, stream>>>(vp_w[1], VPT1);
  k_wtrans<<<dim3(256), blk, 0, stream>>>(op_w[0], OPT0);
  k_wtrans<<<dim3(256), blk, 0, stream>>>(op_w[1], OPT1);
  k_soaw<<<dim3(128), blk, 0, stream>>>(so_w[0], so_b[0], aw_w[0], aw_b[0], SOW0, SOB0);
  k_soaw<<<dim3(128), blk, 0, stream>>>(so_w[1], so_b[1], aw_w[1], aw_b[1], SOW1, SOB1);
  k_bup<<<dim3(2), blk, 0, stream>>>(up_b, BUPP);
  pe_kernel<<<dim3(4096), blk, 0, stream>>>(PET);

  // ---- ground -> XG, gconv ----
  k_transpose<<<dim3(128, 32, NB), blk, 0, stream>>>(ground, XG, 1024);
  gemm_bf16<0><<<dim3(32, 2, NB), blk, 0, stream>>>(WG, XG, gc_b, G, nullptr, nullptr, nullptr, 1024, 256, 256);

  // ---- QF, alpha ----
  k_qf<<<dim3(512, NB), blk, 0, stream>>>(G, PET, QF1, QF2);
  k_alpha<<<dim3(256, NB), blk, 0, stream>>>(G, a_w1, a_b1, a_w2, a_b2, PART);
  k_alpha_fin<<<dim3(NB), blk, 0, stream>>>(PART, AFIN, out_a);

  // ---- sat/osm transposes (XG region reused AFTER gconv) ----
  k_transpose<<<dim3(128, 10, NB), blk, 0, stream>>>(sat, XS, 320);
  k_transpose<<<dim3(128, 10, NB), blk, 0, stream>>>(osm, XO, 320);

  const unsigned short* Xv[2] = {XS, XO};
  const unsigned short* VPT[2] = {VPT0, VPT1};
  const unsigned short* OPT[2] = {OPT0, OPT1};
  const unsigned short* SOWp[2] = {SOW0, SOW1};
  const float* SOBp[2] = {SOB0, SOB1};
  const unsigned short* QFp[2] = {QF1, QF2};

  for (int br = 0; br < 2; ++br) {
    // value conv (osm uses sat weights -- source bug preserved)
    gemm_bf16<0><<<dim3(32, 2, NB), blk, 0, stream>>>(WS, Xv[br], sc_b, VB, nullptr, nullptr, nullptr, 320, 256, 256);
    // value proj
    gemm_bf16<0><<<dim3(32, 2, NB), blk, 0, stream>>>(VPT[br], VB, vp_b[br], VP, nullptr, nullptr, nullptr, 256, 256, 256);
    // sampling offsets + attention logits (padded to 128)
    gemm_bf16<0><<<dim3(32, 1, NB), blk, 0, stream>>>(SOWp[br], QFp[br], SOBp[br], SW, nullptr, nullptr, nullptr, 256, 128, 128);
    // gather (writes OATT, aliases VB after its last read)
    k_sample<<<dim3(NQ, NB), blk, 0, stream>>>(VP, SW, OATT);
    // output proj + residual 2*QF; osm blends with sat branch
    if (br == 0)
      gemm_bf16<1><<<dim3(32, 2, NB), blk, 0, stream>>>(OPT[br], OATT, op_b[br], SATO, QFp[br], nullptr, nullptr, 256, 256, 256);
    else
      gemm_bf16<2><<<dim3(32, 2, NB), blk, 0, stream>>>(OPT[br], OATT, op_b[br], FUSED, QFp[br], SATO, AFIN, 256, 256, 256);
  }

  // ---- up conv -> fp32 out [B][320][4096] ----
  gemm_bf16<3><<<dim3(32, 3, NB), blk, 0, stream>>>(WUP, FUSED, BUPP, out32, nullptr, nullptr, nullptr, 256, 0, 320);
}

// Round 3
// 335.135 us; speedup vs baseline: 3.5420x; 1.4919x over previous
//
#include <hip/hip_runtime.h>
#include <cstddef>
#include <cstdint>

#define NB 8
#define NQ 4096

typedef __attribute__((ext_vector_type(8))) short bfrag8;
typedef __attribute__((ext_vector_type(4))) float facc4;
typedef __attribute__((ext_vector_type(4))) unsigned short us4;
typedef __attribute__((ext_vector_type(8))) unsigned short us8;

__device__ __forceinline__ float bf2f(unsigned short u) {
  union { unsigned int i; float f; } v; v.i = ((unsigned int)u) << 16; return v.f;
}
__device__ __forceinline__ unsigned short f2bf(float f) {
  union { float f; unsigned int i; } v; v.f = f;
  unsigned int r = v.i + 0x7FFFu + ((v.i >> 16) & 1u);
  return (unsigned short)(r >> 16);
}
__device__ __forceinline__ void gload16(const void* g, void* l) {
  __builtin_amdgcn_global_load_lds(
      (const __attribute__((address_space(1))) void*)g,
      (__attribute__((address_space(3))) void*)l, 16, 0, 0);
}

// ---------------- weight prep ----------------
__global__ __launch_bounds__(256) void k_cvt(const float* __restrict__ s,
                                             unsigned short* __restrict__ d, int n) {
  int i = blockIdx.x * 256 + threadIdx.x;
  if (i < n) d[i] = f2bf(s[i]);
}
// combined value weights: WV[m][k] = sum_c vp_w[c][m] * sc_w[c][k]  (m<256, k<320)
__global__ __launch_bounds__(320) void k_wcomb(const float* __restrict__ vp_w0,
                                               const float* __restrict__ vp_w1,
                                               const float* __restrict__ sc_w,
                                               unsigned short* __restrict__ WV0,
                                               unsigned short* __restrict__ WV1) {
  int m = blockIdx.x, br = blockIdx.y, k = threadIdx.x;
  const float* vp = br ? vp_w1 : vp_w0;
  float acc = 0.f;
  for (int c = 0; c < 256; ++c)
    acc = fmaf(vp[c * 256 + m], sc_w[c * 320 + k], acc);
  (br ? WV1 : WV0)[m * 320 + k] = f2bf(acc);
}
// combined value bias: BV[m] = vp_b[m] + sum_c sc_b[c]*vp_w[c][m]
__global__ __launch_bounds__(256) void k_wcombb(const float* __restrict__ vp_w0,
                                                const float* __restrict__ vp_b0,
                                                const float* __restrict__ vp_w1,
                                                const float* __restrict__ vp_b1,
                                                const float* __restrict__ sc_b,
                                                float* __restrict__ BV0,
                                                float* __restrict__ BV1) {
  int m = threadIdx.x, br = blockIdx.x;
  const float* vp = br ? vp_w1 : vp_w0;
  float acc = (br ? vp_b1 : vp_b0)[m];
  for (int c = 0; c < 256; ++c) acc = fmaf(sc_b[c], vp[c * 256 + m], acc);
  (br ? BV1 : BV0)[m] = acc;
}
// up_w [320][256] -> [384][256] bf16 zero-padded
__global__ __launch_bounds__(256) void k_wup(const float* __restrict__ s,
                                             unsigned short* __restrict__ d) {
  int i = blockIdx.x * 256 + threadIdx.x;
  int m = i >> 8, k = i & 255;
  d[i] = (m < 320) ? f2bf(s[m * 256 + k]) : 0;
}
// op_w [k][o] 256x256 -> [o][k] bf16
__global__ __launch_bounds__(256) void k_wtrans(const float* __restrict__ s,
                                                unsigned short* __restrict__ d) {
  int i = blockIdx.x * 256 + threadIdx.x;
  int o = i >> 8, k = i & 255;
  d[i] = f2bf(s[(k << 8) + o]);
}
// so_w [256][64], aw_w [256][32] -> W[128][256] + bias[128]
__global__ __launch_bounds__(256) void k_soaw(const float* __restrict__ so_w,
                                              const float* __restrict__ so_b,
                                              const float* __restrict__ aw_w,
                                              const float* __restrict__ aw_b,
                                              unsigned short* __restrict__ W,
                                              float* __restrict__ Bb) {
  int i = blockIdx.x * 256 + threadIdx.x;
  int row = i >> 8, k = i & 255;
  float v = 0.f;
  if (row < 64) v = so_w[k * 64 + row];
  else if (row < 96) v = aw_w[k * 32 + (row - 64)];
  W[i] = f2bf(v);
  if (i < 128) Bb[i] = (i < 64) ? so_b[i] : ((i < 96) ? aw_b[i - 64] : 0.f);
}
__global__ __launch_bounds__(256) void k_bup(const float* __restrict__ s, float* __restrict__ d) {
  int i = blockIdx.x * 256 + threadIdx.x;
  if (i < 384) d[i] = (i < 320) ? s[i] : 0.f;
}

// ---------------- PE table bf16 [Q][256] ----------------
__global__ __launch_bounds__(256) void pe_kernel(unsigned short* __restrict__ pe) {
  int idx = blockIdx.x * 256 + threadIdx.x;
  int q = idx >> 8, c = idx & 255;
  int h = q >> 6, w = q & 63;
  int k = c >> 2, m = c & 3;
  float dv = expf((float)(2 * k) * (-9.210340371976184f / 128.0f));
  float arg = ((m < 2) ? (float)w : (float)h) * dv;
  pe[idx] = f2bf(((m & 1) == 0) ? sinf(arg) : cosf(arg));
}

// ---------------- transpose: [B][K][4096] f32 -> [B][4096][K] bf16, 64k x 32q tiles
__global__ __launch_bounds__(256) void k_transpose(const float* __restrict__ src,
                                                   unsigned short* __restrict__ dst, int K) {
  int b = blockIdx.z;
  int k0 = blockIdx.y * 64, n0 = blockIdx.x * 32;
  const float* s = src + (size_t)b * K * NQ;
  unsigned short* d = dst + (size_t)b * NQ * K;
  __shared__ float tile[64][33];
  int t = threadIdx.x;
  int r = t >> 2, c8 = (t & 3) * 8;
  float4 v0 = *reinterpret_cast<const float4*>(&s[(size_t)(k0 + r) * NQ + n0 + c8]);
  float4 v1 = *reinterpret_cast<const float4*>(&s[(size_t)(k0 + r) * NQ + n0 + c8 + 4]);
  tile[r][c8 + 0] = v0.x; tile[r][c8 + 1] = v0.y; tile[r][c8 + 2] = v0.z; tile[r][c8 + 3] = v0.w;
  tile[r][c8 + 4] = v1.x; tile[r][c8 + 5] = v1.y; tile[r][c8 + 6] = v1.z; tile[r][c8 + 7] = v1.w;
  __syncthreads();
  int qr = t >> 3, kg = (t & 7) * 8;
  us8 pk;
#pragma unroll
  for (int j = 0; j < 8; ++j) pk[j] = f2bf(tile[kg + j][qr]);
  *reinterpret_cast<us8*>(&d[(size_t)(n0 + qr) * K + k0 + kg]) = pk;
}

// ---------------- unified bf16 MFMA GEMM ----------------
struct GArgs {
  const unsigned short* W[2];
  const unsigned short* X[2];
  const float* bias[2];
  void* out[2];
  const unsigned short* res[2]; // [4096][128] broadcast residual (MODE 2)
  float rscale[2];              // MODE1: acc scale; MODE2: res scale; MODE3/4: PET scale
  const unsigned short* G;      // MODE3/4 residual (per-batch [N][256])
  const unsigned short* PET;    // MODE3/4 broadcast residual [N][256]
  const unsigned short* other;  // MODE4 blend
  const float* afin;            // MODE4 blend
  int K, ldm, Mreal, bmask, brshift;
};
// MODE 0: out = acc + bias (bf16)
// MODE 1: out = rscale*acc + bias (bf16)
// MODE 2: out = acc + rscale*res[n*128+m] (bf16)
// MODE 3: out = acc + bias + 2*G + rscale*PET (bf16)
// MODE 4: out = a*other + (1-a)*(acc + bias + 2*G + rscale*PET) (bf16)
// MODE 5: out f32 [B][Mreal][4096] = acc + bias
template <int MODE>
__global__ __launch_bounds__(256) void gemm_bf16(GArgs g) {
  __shared__ unsigned short As[8192]; // [128][64] swizzled
  __shared__ unsigned short Bs[8192];
  const int t = threadIdx.x;
  const int lane = t & 63, w = t >> 6;
  const int z = blockIdx.z;
  const int b = z & g.bmask, br = z >> g.brshift;
  const int K = g.K;
  const int n0 = blockIdx.x * 128, m0 = blockIdx.y * 128;
  const unsigned short* W = g.W[br];
  const unsigned short* Xb = g.X[br] + (size_t)b * NQ * K;

  const unsigned short* asrc[4];
  const unsigned short* bsrc[4];
  unsigned short* adst[4];
  unsigned short* bdst[4];
#pragma unroll
  for (int i = 0; i < 4; ++i) {
    int cid = i * 256 + t;
    int row = cid >> 3;
    int cc = (cid & 7) ^ (row & 7);
    asrc[i] = W + (size_t)(m0 + row) * K + cc * 8;
    bsrc[i] = Xb + (size_t)(n0 + row) * K + cc * 8;
    adst[i] = &As[i * 2048 + w * 512];
    bdst[i] = &Bs[i * 2048 + w * 512];
  }

  const int wm = (w >> 1) * 64, wn = (w & 1) * 64;
  const int l15 = lane & 15, l4 = lane >> 4;
  facc4 acc[4][4];
#pragma unroll
  for (int i = 0; i < 4; ++i)
#pragma unroll
    for (int j = 0; j < 4; ++j) acc[i][j] = facc4{0.f, 0.f, 0.f, 0.f};

  for (int k0 = 0; k0 < K; k0 += 64) {
    if (k0) __syncthreads();
#pragma unroll
    for (int i = 0; i < 4; ++i) {
      gload16(asrc[i], adst[i]);
      gload16(bsrc[i], bdst[i]);
      asrc[i] += 64; bsrc[i] += 64;
    }
    __syncthreads();
#pragma unroll
    for (int kk = 0; kk < 2; ++kk) {
      bfrag8 af[4], bf[4];
#pragma unroll
      for (int mi = 0; mi < 4; ++mi) {
        int row = wm + mi * 16 + l15;
        af[mi] = *reinterpret_cast<const bfrag8*>(
            &As[row * 64 + (((kk * 4 + l4) ^ (row & 7)) * 8)]);
      }
#pragma unroll
      for (int ni = 0; ni < 4; ++ni) {
        int row = wn + ni * 16 + l15;
        bf[ni] = *reinterpret_cast<const bfrag8*>(
            &Bs[row * 64 + (((kk * 4 + l4) ^ (row & 7)) * 8)]);
      }
#pragma unroll
      for (int mi = 0; mi < 4; ++mi)
#pragma unroll
        for (int ni = 0; ni < 4; ++ni)
          acc[mi][ni] = __builtin_amdgcn_mfma_f32_16x16x32_bf16(af[mi], bf[ni], acc[mi][ni], 0, 0, 0);
    }
  }

  const size_t bq = (size_t)b * NQ;
#pragma unroll
  for (int mi = 0; mi < 4; ++mi) {
#pragma unroll
    for (int ni = 0; ni < 4; ++ni) {
      int m = m0 + wm + mi * 16 + l4 * 4;
      int n = n0 + wn + ni * 16 + l15;
      facc4 v = acc[mi][ni];
      if constexpr (MODE == 5) {
        float* o32 = (float*)g.out[br];
#pragma unroll
        for (int r = 0; r < 4; ++r)
          if (m + r < g.Mreal)
            o32[((size_t)b * g.Mreal + (m + r)) * NQ + n] = v[r] + g.bias[br][m + r];
      } else {
        unsigned short* o16 = (unsigned short*)g.out[br];
        float rv[4] = {v[0], v[1], v[2], v[3]};
        if constexpr (MODE == 1) {
          float sc = g.rscale[br];
#pragma unroll
          for (int r = 0; r < 4; ++r) rv[r] *= sc;
        }
        if constexpr (MODE != 2) {
          float4 bv = *reinterpret_cast<const float4*>(&g.bias[br][m]);
          rv[0] += bv.x; rv[1] += bv.y; rv[2] += bv.z; rv[3] += bv.w;
        }
        if constexpr (MODE == 2) {
          float sc = g.rscale[br];
          us4 rr = *reinterpret_cast<const us4*>(&g.res[br][(size_t)n * 128 + m]);
#pragma unroll
          for (int r = 0; r < 4; ++r) rv[r] += sc * bf2f(rr[r]);
        }
        if constexpr (MODE == 3 || MODE == 4) {
          float sc = g.rscale[br];
          us4 gv = *reinterpret_cast<const us4*>(&g.G[(bq + n) * 256 + m]);
          us4 pv = *reinterpret_cast<const us4*>(&g.PET[(size_t)n * 256 + m]);
#pragma unroll
          for (int r = 0; r < 4; ++r) rv[r] += 2.f * bf2f(gv[r]) + sc * bf2f(pv[r]);
        }
        if constexpr (MODE == 4) {
          float a = g.afin[b];
          us4 ov = *reinterpret_cast<const us4*>(&g.other[(bq + n) * 256 + m]);
#pragma unroll
          for (int r = 0; r < 4; ++r) rv[r] = a * bf2f(ov[r]) + (1.f - a) * rv[r];
        }
        us4 pk;
#pragma unroll
        for (int r = 0; r < 4; ++r) pk[r] = f2bf(rv[r]);
        *reinterpret_cast<us4*>(&o16[(bq + n) * g.ldm + m]) = pk;
      }
    }
  }
}

// ---------------- alpha gate ----------------
__global__ __launch_bounds__(256) void k_alpha(const unsigned short* __restrict__ G,
                                               const float* __restrict__ w1,
                                               const float* __restrict__ b1,
                                               const float* __restrict__ w2,
                                               const float* __restrict__ b2,
                                               float* __restrict__ partial) {
  int b = blockIdx.y;
  int qbase = blockIdx.x * 16;
  __shared__ float gs[16][256];
  __shared__ float wsum[4];
  int t = threadIdx.x;
  const unsigned short* gp = G + ((size_t)b * NQ + qbase) * 256;
#pragma unroll
  for (int i = t; i < 512; i += 256) {
    bfrag8 v = *reinterpret_cast<const bfrag8*>(&gp[i * 8]);
    int row = i >> 5, col = (i & 31) * 8;
#pragma unroll
    for (int j = 0; j < 8; ++j) gs[row][col + j] = bf2f((unsigned short)v[j]);
  }
  __syncthreads();
  int wv = t >> 6, lane = t & 63;
  float a0 = 0.f, a1 = 0.f, a2 = 0.f, a3 = 0.f;
  const float* g0 = gs[wv * 4 + 0];
  const float* g1 = gs[wv * 4 + 1];
  const float* g2 = gs[wv * 4 + 2];
  const float* g3 = gs[wv * 4 + 3];
#pragma unroll 4
  for (int k = 0; k < 256; ++k) {
    float wk = w1[k * 64 + lane];
    a0 = fmaf(g0[k], wk, a0); a1 = fmaf(g1[k], wk, a1);
    a2 = fmaf(g2[k], wk, a2); a3 = fmaf(g3[k], wk, a3);
  }
  float b1l = b1[lane], w2l = w2[lane];
  a0 = fmaxf(a0 + b1l, 0.f) * w2l; a1 = fmaxf(a1 + b1l, 0.f) * w2l;
  a2 = fmaxf(a2 + b1l, 0.f) * w2l; a3 = fmaxf(a3 + b1l, 0.f) * w2l;
#pragma unroll
  for (int off = 32; off; off >>= 1) {
    a0 += __shfl_xor(a0, off); a1 += __shfl_xor(a1, off);
    a2 += __shfl_xor(a2, off); a3 += __shfl_xor(a3, off);
  }
  if (lane == 0) {
    float bb = b2[0];
    float s = 1.f / (1.f + expf(-(a0 + bb))) + 1.f / (1.f + expf(-(a1 + bb))) +
              1.f / (1.f + expf(-(a2 + bb))) + 1.f / (1.f + expf(-(a3 + bb)));
    wsum[wv] = s;
  }
  __syncthreads();
  if (t == 0) partial[(size_t)b * 256 + blockIdx.x] = wsum[0] + wsum[1] + wsum[2] + wsum[3];
}

__global__ __launch_bounds__(256) void k_alpha_fin(const float* __restrict__ partial,
                                                   float* __restrict__ afin,
                                                   float* __restrict__ out_a) {
  int b = blockIdx.x;
  __shared__ float sm[256];
  sm[threadIdx.x] = partial[(size_t)b * 256 + threadIdx.x];
  __syncthreads();
  for (int st = 128; st; st >>= 1) {
    if (threadIdx.x < st) sm[threadIdx.x] += sm[threadIdx.x + st];
    __syncthreads();
  }
  if (threadIdx.x == 0) {
    float a = sm[0] * (1.f / 4096.f);
    afin[b] = a;
    out_a[b] = a;
  }
}

// ---------------- deformable bilinear sampling, vectorized 8ch/thread ----------------
// block: 8 queries; thread t: qi=t>>5, head=(t&31)>>2, hdg=t&3 (8 channels)
__global__ __launch_bounds__(256) void k_sample(const unsigned short* __restrict__ VP0,
                                                const unsigned short* __restrict__ VP1,
                                                const unsigned short* __restrict__ SWb,
                                                unsigned short* __restrict__ OATT0,
                                                unsigned short* __restrict__ OATT1) {
  int y = blockIdx.y;
  int b = y & 7, br = y >> 3;
  int q0 = blockIdx.x * 8;
  const unsigned short* VP = (br ? VP1 : VP0) + (size_t)b * NQ * 256;
  const unsigned short* SWp = SWb + (((size_t)br * NB + b) * NQ + q0) * 128;
  unsigned short* OATT = (br ? OATT1 : OATT0) + ((size_t)b * NQ + q0) * 256;
  __shared__ unsigned short sws[1024];
  int t = threadIdx.x;
  *reinterpret_cast<us4*>(&sws[t * 4]) = *reinterpret_cast<const us4*>(&SWp[t * 4]);
  __syncthreads();
  int qi = t >> 5, ss = t & 31, head = ss >> 2, hdg = ss & 3;
  int q = q0 + qi;
  const unsigned short* sw = &sws[qi * 128];
  float l0 = bf2f(sw[64 + head * 4 + 0]);
  float l1 = bf2f(sw[64 + head * 4 + 1]);
  float l2 = bf2f(sw[64 + head * 4 + 2]);
  float l3 = bf2f(sw[64 + head * 4 + 3]);
  float mx = fmaxf(fmaxf(l0, l1), fmaxf(l2, l3));
  float e0 = expf(l0 - mx), e1 = expf(l1 - mx), e2 = expf(l2 - mx), e3 = expf(l3 - mx);
  float inv = 1.f / (e0 + e1 + e2 + e3);
  float aw[4] = {e0 * inv, e1 * inv, e2 * inv, e3 * inv};
  float rpx = (float)(q & 63) * (64.f / 63.f) - 0.5f;
  float rpy = (float)(q >> 6) * (64.f / 63.f) - 0.5f;
  const unsigned short* vb = VP + head * 32 + hdg * 8;
  float acc[8] = {};
#pragma unroll
  for (int p = 0; p < 4; ++p) {
    float px = rpx + bf2f(sw[head * 8 + p * 2 + 0]);
    float py = rpy + bf2f(sw[head * 8 + p * 2 + 1]);
    float fx = floorf(px), fy = floorf(py);
    int x0 = (int)fx, y0 = (int)fy;
    float wx = px - fx, wy = py - fy;
#pragma unroll
    for (int dy = 0; dy < 2; ++dy) {
#pragma unroll
      for (int dx = 0; dx < 2; ++dx) {
        int xi = x0 + dx, yi = y0 + dy;
        if (xi >= 0 && xi < 64 && yi >= 0 && yi < 64) {
          float wa = aw[p] * (dx ? wx : 1.f - wx) * (dy ? wy : 1.f - wy);
          bfrag8 v = *reinterpret_cast<const bfrag8*>(&vb[(size_t)(yi * 64 + xi) * 256]);
#pragma unroll
          for (int j = 0; j < 8; ++j) acc[j] = fmaf(wa, bf2f((unsigned short)v[j]), acc[j]);
        }
      }
    }
  }
  us8 o;
#pragma unroll
  for (int j = 0; j < 8; ++j) o[j] = f2bf(acc[j]);
  *reinterpret_cast<us8*>(&OATT[qi * 256 + ss * 8]) = o;
}

extern "C" void kernel_launch(void* const* d_in, const int* in_sizes, int n_in,
                              void* d_out, int out_size, void* d_ws, size_t ws_size,
                              hipStream_t stream) {
  const float* ground = (const float*)d_in[0];
  const float* sat = (const float*)d_in[1];
  const float* osm = (const float*)d_in[2];
  const float* gc_w = (const float*)d_in[3];
  const float* gc_b = (const float*)d_in[4];
  const float* sc_w = (const float*)d_in[5];
  const float* sc_b = (const float*)d_in[6];
  const float* up_w = (const float*)d_in[7];
  const float* up_b = (const float*)d_in[8];
  const float* a_w1 = (const float*)d_in[9];
  const float* a_b1 = (const float*)d_in[10];
  const float* a_w2 = (const float*)d_in[11];
  const float* a_b2 = (const float*)d_in[12];
  const float* vp_w[2] = {(const float*)d_in[13], (const float*)d_in[21]};
  const float* vp_b[2] = {(const float*)d_in[14], (const float*)d_in[22]};
  const float* so_w[2] = {(const float*)d_in[15], (const float*)d_in[23]};
  const float* so_b[2] = {(const float*)d_in[16], (const float*)d_in[24]};
  const float* aw_w[2] = {(const float*)d_in[17], (const float*)d_in[25]};
  const float* aw_b[2] = {(const float*)d_in[18], (const float*)d_in[26]};
  const float* op_w[2] = {(const float*)d_in[19], (const float*)d_in[27]};
  const float* op_b[2] = {(const float*)d_in[20], (const float*)d_in[28]};

  char* wsb = (char*)d_ws;
  const size_t MBy = 1 << 20;
  unsigned short* PET  = (unsigned short*)(wsb);                 // 2 MB
  unsigned short* WG   = (unsigned short*)(wsb + 2 * MBy);       // 512 KB
  unsigned short* WV0  = (unsigned short*)(wsb + 2 * MBy + 524288);   // 160 KB
  unsigned short* WV1  = (unsigned short*)(wsb + 2 * MBy + 786432);   // 160 KB
  unsigned short* WUP  = (unsigned short*)(wsb + 3 * MBy);            // 192 KB
  unsigned short* OPT0 = (unsigned short*)(wsb + 3 * MBy + 262144);   // 128 KB
  unsigned short* OPT1 = (unsigned short*)(wsb + 3 * MBy + 393216);   // 128 KB
  unsigned short* SOW0 = (unsigned short*)(wsb + 3 * MBy + 524288);   // 64 KB
  unsigned short* SOW1 = (unsigned short*)(wsb + 3 * MBy + 589824);   // 64 KB
  unsigned short* PESO0 = (unsigned short*)(wsb + 4 * MBy);           // 1 MB
  unsigned short* PESO1 = (unsigned short*)(wsb + 5 * MBy);           // 1 MB
  float* SOB0 = (float*)(wsb + 6 * MBy);
  float* SOB1 = (float*)(wsb + 6 * MBy + 1024);
  float* BV0  = (float*)(wsb + 6 * MBy + 2048);
  float* BV1  = (float*)(wsb + 6 * MBy + 4096);
  float* BUPP = (float*)(wsb + 6 * MBy + 8192);
  float* PART = (float*)(wsb + 6 * MBy + 16384);  // 8 KB
  float* AFIN = (float*)(wsb + 6 * MBy + 32768);
  unsigned short* G     = (unsigned short*)(wsb + 8 * MBy);    // 16 MB
  unsigned short* XS    = (unsigned short*)(wsb + 24 * MBy);   // 20 MB ; OATT1 alias
  unsigned short* XO    = (unsigned short*)(wsb + 44 * MBy);   // 20 MB ; SATO alias
  unsigned short* VP0b  = (unsigned short*)(wsb + 64 * MBy);   // 16 MB
  unsigned short* VP1b  = (unsigned short*)(wsb + 80 * MBy);   // 16 MB
  unsigned short* SW    = (unsigned short*)(wsb + 96 * MBy);   // 16 MB [2][B][Q][128]
  unsigned short* OATT0 = (unsigned short*)(wsb + 112 * MBy);  // 16 MB ; FUSED alias
  unsigned short* XG    = (unsigned short*)(wsb + 64 * MBy);   // 64 MB transient (over VP0,VP1,SW,OATT0)
  unsigned short* OATT1 = XS;
  unsigned short* SATO  = XO;
  unsigned short* FUSED = OATT0;

  float* out32 = (float*)d_out;
  float* out_a = out32 + (size_t)NB * 320 * NQ;

  dim3 blk(256);
  // ---- prep ----
  pe_kernel<<<dim3(4096), blk, 0, stream>>>(PET);
  k_cvt<<<dim3(1024), blk, 0, stream>>>(gc_w, WG, 262144);
  k_wcomb<<<dim3(256, 2), dim3(320), 0, stream>>>(vp_w[0], vp_w[1], sc_w, WV0, WV1);
  k_wcombb<<<dim3(2), blk, 0, stream>>>(vp_w[0], vp_b[0], vp_w[1], vp_b[1], sc_b, BV0, BV1);
  k_wup<<<dim3(384), blk, 0, stream>>>(up_w, WUP);
  k_bup<<<dim3(2), blk, 0, stream>>>(up_b, BUPP);
  k_wtrans<<<dim3(256), blk, 0, stream>>>(op_w[0], OPT0);
  k_wtrans<<<dim3(256), blk, 0, stream>>>(op_w[1], OPT1);
  k_soaw<<<dim3(128), blk, 0, stream>>>(so_w[0], so_b[0], aw_w[0], aw_b[0], SOW0, SOB0);
  k_soaw<<<dim3(128), blk, 0, stream>>>(so_w[1], so_b[1], aw_w[1], aw_b[1], SOW1, SOB1);

  // ---- PESO_br = s_br*(PE @ soaw_w_br) + bias_br : [4096][128] bf16 ----
  {
    GArgs a = {};
    a.W[0] = SOW0; a.W[1] = SOW1;
    a.X[0] = PET;  a.X[1] = PET;
    a.bias[0] = SOB0; a.bias[1] = SOB1;
    a.out[0] = PESO0; a.out[1] = PESO1;
    a.rscale[0] = 1.f; a.rscale[1] = 2.f;
    a.K = 256; a.ldm = 128; a.bmask = 0; a.brshift = 0;
    gemm_bf16<1><<<dim3(32, 1, 2), blk, 0, stream>>>(a);
  }

  // ---- ground transpose + gconv ----
  k_transpose<<<dim3(128, 16, NB), blk, 0, stream>>>(ground, XG, 1024);
  {
    GArgs a = {};
    a.W[0] = WG; a.W[1] = WG; a.X[0] = XG; a.X[1] = XG;
    a.bias[0] = gc_b; a.bias[1] = gc_b;
    a.out[0] = G; a.out[1] = G;
    a.K = 1024; a.ldm = 256; a.bmask = 7; a.brshift = 31;
    gemm_bf16<0><<<dim3(32, 2, NB), blk, 0, stream>>>(a);
  }

  // ---- alpha ----
  k_alpha<<<dim3(256, NB), blk, 0, stream>>>(G, a_w1, a_b1, a_w2, a_b2, PART);
  k_alpha_fin<<<dim3(NB), blk, 0, stream>>>(PART, AFIN, out_a);

  // ---- sat/osm transposes (XG dead after gconv) ----
  k_transpose<<<dim3(128, 5, NB), blk, 0, stream>>>(sat, XS, 320);
  k_transpose<<<dim3(128, 5, NB), blk, 0, stream>>>(osm, XO, 320);

  // ---- SW_br = G @ soaw_w_br + PESO_br  (both branches, z=16) ----
  {
    GArgs a = {};
    a.W[0] = SOW0; a.W[1] = SOW1;
    a.X[0] = G; a.X[1] = G;
    a.out[0] = SW; a.out[1] = SW + (size_t)NB * NQ * 128;
    a.res[0] = PESO0; a.res[1] = PESO1;
    a.rscale[0] = 1.f; a.rscale[1] = 1.f;
    a.K = 256; a.ldm = 128; a.bmask = 7; a.brshift = 3;
    gemm_bf16<2><<<dim3(32, 1, 16), blk, 0, stream>>>(a);
  }

  // ---- VP_br = X_br @ WV_br + BV_br (combined conv+proj, both branches) ----
  {
    GArgs a = {};
    a.W[0] = WV0; a.W[1] = WV1;
    a.X[0] = XS; a.X[1] = XO;
    a.bias[0] = BV0; a.bias[1] = BV1;
    a.out[0] = VP0b; a.out[1] = VP1b;
    a.K = 320; a.ldm = 256; a.bmask = 7; a.brshift = 3;
    gemm_bf16<0><<<dim3(32, 2, 16), blk, 0, stream>>>(a);
  }

  // ---- sampling (both branches) ----
  k_sample<<<dim3(512, 16), blk, 0, stream>>>(VP0b, VP1b, SW, OATT0, OATT1);

  // ---- output proj br0 -> SATO ----
  {
    GArgs a = {};
    a.W[0] = OPT0; a.W[1] = OPT0;
    a.X[0] = OATT0; a.X[1] = OATT0;
    a.bias[0] = op_b[0]; a.bias[1] = op_b[0];
    a.out[0] = SATO; a.out[1] = SATO;
    a.rscale[0] = 2.f; a.rscale[1] = 2.f;
    a.G = G; a.PET = PET;
    a.K = 256; a.ldm = 256; a.bmask = 7; a.brshift = 31;
    gemm_bf16<3><<<dim3(32, 2, NB), blk, 0, stream>>>(a);
  }
  // ---- output proj br1 + blend -> FUSED ----
  {
    GArgs a = {};
    a.W[0] = OPT1; a.W[1] = OPT1;
    a.X[0] = OATT1; a.X[1] = OATT1;
    a.bias[0] = op_b[1]; a.bias[1] = op_b[1];
    a.out[0] = FUSED; a.out[1] = FUSED;
    a.rscale[0] = 4.f; a.rscale[1] = 4.f;
    a.G = G; a.PET = PET;
    a.other = SATO; a.afin = AFIN;
    a.K = 256; a.ldm = 256; a.bmask = 7; a.brshift = 31;
    gemm_bf16<4><<<dim3(32, 2, NB), blk, 0, stream>>>(a);
  }
  // ---- up conv -> f32 out ----
  {
    GArgs a = {};
    a.W[0] = WUP; a.W[1] = WUP;
    a.X[0] = FUSED; a.X[1] = FUSED;
    a.bias[0] = BUPP; a.bias[1] = BUPP;
    a.out[0] = out32; a.out[1] = out32;
    a.K = 256; a.ldm = 0; a.Mreal = 320; a.bmask = 7; a.brshift = 31;
    gemm_bf16<5><<<dim3(32, 3, NB), blk, 0, stream>>>(a);
  }
}

// Round 4
// 333.910 us; speedup vs baseline: 3.5550x; 1.0037x over previous
//
#include <hip/hip_runtime.h>
#include <cstddef>
#include <cstdint>

#define NB 8
#define NQ 4096

typedef __attribute__((ext_vector_type(8))) short bfrag8;
typedef __attribute__((ext_vector_type(4))) float facc4;
typedef __attribute__((ext_vector_type(4))) unsigned short us4;
typedef __attribute__((ext_vector_type(8))) unsigned short us8;

__device__ __forceinline__ float bf2f(unsigned short u) {
  union { unsigned int i; float f; } v; v.i = ((unsigned int)u) << 16; return v.f;
}
__device__ __forceinline__ unsigned short f2bf(float f) {
  union { float f; unsigned int i; } v; v.f = f;
  unsigned int r = v.i + 0x7FFFu + ((v.i >> 16) & 1u);
  return (unsigned short)(r >> 16);
}
__device__ __forceinline__ void gload16(const void* g, void* l) {
  __builtin_amdgcn_global_load_lds(
      (const __attribute__((address_space(1))) void*)g,
      (__attribute__((address_space(3))) void*)l, 16, 0, 0);
}

// ---------------- weight prep ----------------
__global__ __launch_bounds__(256) void k_cvt(const float* __restrict__ s,
                                             unsigned short* __restrict__ d, int n) {
  int i = blockIdx.x * 256 + threadIdx.x;
  if (i < n) d[i] = f2bf(s[i]);
}
// combined value weights: WV[m][k] = sum_c vp_w[c][m] * sc_w[c][k]  (m<256, k<320)
__global__ __launch_bounds__(320) void k_wcomb(const float* __restrict__ vp_w0,
                                               const float* __restrict__ vp_w1,
                                               const float* __restrict__ sc_w,
                                               unsigned short* __restrict__ WV0,
                                               unsigned short* __restrict__ WV1) {
  int m = blockIdx.x, br = blockIdx.y, k = threadIdx.x;
  const float* vp = br ? vp_w1 : vp_w0;
  float acc = 0.f;
  for (int c = 0; c < 256; ++c)
    acc = fmaf(vp[c * 256 + m], sc_w[c * 320 + k], acc);
  (br ? WV1 : WV0)[m * 320 + k] = f2bf(acc);
}
// combined value bias: BV[m] = vp_b[m] + sum_c sc_b[c]*vp_w[c][m]
__global__ __launch_bounds__(256) void k_wcombb(const float* __restrict__ vp_w0,
                                                const float* __restrict__ vp_b0,
                                                const float* __restrict__ vp_w1,
                                                const float* __restrict__ vp_b1,
                                                const float* __restrict__ sc_b,
                                                float* __restrict__ BV0,
                                                float* __restrict__ BV1) {
  int m = threadIdx.x, br = blockIdx.x;
  const float* vp = br ? vp_w1 : vp_w0;
  float acc = (br ? vp_b1 : vp_b0)[m];
  for (int c = 0; c < 256; ++c) acc = fmaf(sc_b[c], vp[c * 256 + m], acc);
  (br ? BV1 : BV0)[m] = acc;
}
// up_w [320][256] -> [384][256] bf16 zero-padded
__global__ __launch_bounds__(256) void k_wup(const float* __restrict__ s,
                                             unsigned short* __restrict__ d) {
  int i = blockIdx.x * 256 + threadIdx.x;
  int m = i >> 8, k = i & 255;
  d[i] = (m < 320) ? f2bf(s[m * 256 + k]) : 0;
}
// op_w [k][o] 256x256 -> [o][k] bf16
__global__ __launch_bounds__(256) void k_wtrans(const float* __restrict__ s,
                                                unsigned short* __restrict__ d) {
  int i = blockIdx.x * 256 + threadIdx.x;
  int o = i >> 8, k = i & 255;
  d[i] = f2bf(s[(k << 8) + o]);
}
// so_w [256][64], aw_w [256][32] -> W[128][256] + bias[128]
__global__ __launch_bounds__(256) void k_soaw(const float* __restrict__ so_w,
                                              const float* __restrict__ so_b,
                                              const float* __restrict__ aw_w,
                                              const float* __restrict__ aw_b,
                                              unsigned short* __restrict__ W,
                                              float* __restrict__ Bb) {
  int i = blockIdx.x * 256 + threadIdx.x;
  int row = i >> 8, k = i & 255;
  float v = 0.f;
  if (row < 64) v = so_w[k * 64 + row];
  else if (row < 96) v = aw_w[k * 32 + (row - 64)];
  W[i] = f2bf(v);
  if (i < 128) Bb[i] = (i < 64) ? so_b[i] : ((i < 96) ? aw_b[i - 64] : 0.f);
}
__global__ __launch_bounds__(256) void k_bup(const float* __restrict__ s, float* __restrict__ d) {
  int i = blockIdx.x * 256 + threadIdx.x;
  if (i < 384) d[i] = (i < 320) ? s[i] : 0.f;
}

// ---------------- PE table bf16 [Q][256] ----------------
__global__ __launch_bounds__(256) void pe_kernel(unsigned short* __restrict__ pe) {
  int idx = blockIdx.x * 256 + threadIdx.x;
  int q = idx >> 8, c = idx & 255;
  int h = q >> 6, w = q & 63;
  int k = c >> 2, m = c & 3;
  float dv = expf((float)(2 * k) * (-9.210340371976184f / 128.0f));
  float arg = ((m < 2) ? (float)w : (float)h) * dv;
  pe[idx] = f2bf(((m & 1) == 0) ? sinf(arg) : cosf(arg));
}

// ---------------- transpose: [B][K][4096] f32 -> [B][4096][K] bf16, 64k x 32q tiles
__global__ __launch_bounds__(256) void k_transpose(const float* __restrict__ src,
                                                   unsigned short* __restrict__ dst, int K) {
  int b = blockIdx.z;
  int k0 = blockIdx.y * 64, n0 = blockIdx.x * 32;
  const float* s = src + (size_t)b * K * NQ;
  unsigned short* d = dst + (size_t)b * NQ * K;
  __shared__ float tile[64][33];
  int t = threadIdx.x;
  int r = t >> 2, c8 = (t & 3) * 8;
  float4 v0 = *reinterpret_cast<const float4*>(&s[(size_t)(k0 + r) * NQ + n0 + c8]);
  float4 v1 = *reinterpret_cast<const float4*>(&s[(size_t)(k0 + r) * NQ + n0 + c8 + 4]);
  tile[r][c8 + 0] = v0.x; tile[r][c8 + 1] = v0.y; tile[r][c8 + 2] = v0.z; tile[r][c8 + 3] = v0.w;
  tile[r][c8 + 4] = v1.x; tile[r][c8 + 5] = v1.y; tile[r][c8 + 6] = v1.z; tile[r][c8 + 7] = v1.w;
  __syncthreads();
  int qr = t >> 3, kg = (t & 7) * 8;
  us8 pk;
#pragma unroll
  for (int j = 0; j < 8; ++j) pk[j] = f2bf(tile[kg + j][qr]);
  *reinterpret_cast<us8*>(&d[(size_t)(n0 + qr) * K + k0 + kg]) = pk;
}

// ---------------- unified bf16 MFMA GEMM ----------------
struct GArgs {
  const unsigned short* W[2];
  const unsigned short* X[2];
  const float* bias[2];
  void* out[2];
  const unsigned short* res[2]; // [4096][128] broadcast residual (MODE 2)
  float rscale[2];              // MODE1: acc scale; MODE2: res scale; MODE3/4: PET scale
  const unsigned short* G;      // MODE3/4 residual (per-batch [N][256])
  const unsigned short* PET;    // MODE3/4 broadcast residual [N][256]
  const unsigned short* other;  // MODE4 blend
  const float* afin;            // MODE4 blend
  int K, ldm, Mreal, bmask, brshift;
};
// MODE 0: out = acc + bias (bf16)
// MODE 1: out = rscale*acc + bias (bf16)
// MODE 2: out = acc + rscale*res[n*128+m] (bf16)
// MODE 3: out = acc + bias + 2*G + rscale*PET (bf16)
// MODE 4: out = a*other + (1-a)*(acc + bias + 2*G + rscale*PET) (bf16)
// MODE 5: out f32 [B][Mreal][4096] = acc + bias
template <int MODE>
__global__ __launch_bounds__(256) void gemm_bf16(GArgs g) {
  __shared__ unsigned short As[8192]; // [128][64] swizzled
  __shared__ unsigned short Bs[8192];
  const int t = threadIdx.x;
  const int lane = t & 63, w = t >> 6;
  const int z = blockIdx.z;
  const int b = z & g.bmask, br = z >> g.brshift;
  const int K = g.K;
  const int n0 = blockIdx.x * 128, m0 = blockIdx.y * 128;
  const unsigned short* W = g.W[br];
  const unsigned short* Xb = g.X[br] + (size_t)b * NQ * K;

  const unsigned short* asrc[4];
  const unsigned short* bsrc[4];
  unsigned short* adst[4];
  unsigned short* bdst[4];
#pragma unroll
  for (int i = 0; i < 4; ++i) {
    int cid = i * 256 + t;
    int row = cid >> 3;
    int cc = (cid & 7) ^ (row & 7);
    asrc[i] = W + (size_t)(m0 + row) * K + cc * 8;
    bsrc[i] = Xb + (size_t)(n0 + row) * K + cc * 8;
    adst[i] = &As[i * 2048 + w * 512];
    bdst[i] = &Bs[i * 2048 + w * 512];
  }

  const int wm = (w >> 1) * 64, wn = (w & 1) * 64;
  const int l15 = lane & 15, l4 = lane >> 4;
  facc4 acc[4][4];
#pragma unroll
  for (int i = 0; i < 4; ++i)
#pragma unroll
    for (int j = 0; j < 4; ++j) acc[i][j] = facc4{0.f, 0.f, 0.f, 0.f};

  for (int k0 = 0; k0 < K; k0 += 64) {
    if (k0) __syncthreads();
#pragma unroll
    for (int i = 0; i < 4; ++i) {
      gload16(asrc[i], adst[i]);
      gload16(bsrc[i], bdst[i]);
      asrc[i] += 64; bsrc[i] += 64;
    }
    __syncthreads();
#pragma unroll
    for (int kk = 0; kk < 2; ++kk) {
      bfrag8 af[4], bf[4];
#pragma unroll
      for (int mi = 0; mi < 4; ++mi) {
        int row = wm + mi * 16 + l15;
        af[mi] = *reinterpret_cast<const bfrag8*>(
            &As[row * 64 + (((kk * 4 + l4) ^ (row & 7)) * 8)]);
      }
#pragma unroll
      for (int ni = 0; ni < 4; ++ni) {
        int row = wn + ni * 16 + l15;
        bf[ni] = *reinterpret_cast<const bfrag8*>(
            &Bs[row * 64 + (((kk * 4 + l4) ^ (row & 7)) * 8)]);
      }
#pragma unroll
      for (int mi = 0; mi < 4; ++mi)
#pragma unroll
        for (int ni = 0; ni < 4; ++ni)
          acc[mi][ni] = __builtin_amdgcn_mfma_f32_16x16x32_bf16(af[mi], bf[ni], acc[mi][ni], 0, 0, 0);
    }
  }

  const size_t bq = (size_t)b * NQ;
#pragma unroll
  for (int mi = 0; mi < 4; ++mi) {
#pragma unroll
    for (int ni = 0; ni < 4; ++ni) {
      int m = m0 + wm + mi * 16 + l4 * 4;
      int n = n0 + wn + ni * 16 + l15;
      facc4 v = acc[mi][ni];
      if constexpr (MODE == 5) {
        float* o32 = (float*)g.out[br];
#pragma unroll
        for (int r = 0; r < 4; ++r)
          if (m + r < g.Mreal)
            o32[((size_t)b * g.Mreal + (m + r)) * NQ + n] = v[r] + g.bias[br][m + r];
      } else {
        unsigned short* o16 = (unsigned short*)g.out[br];
        float rv[4] = {v[0], v[1], v[2], v[3]};
        if constexpr (MODE == 1) {
          float sc = g.rscale[br];
#pragma unroll
          for (int r = 0; r < 4; ++r) rv[r] *= sc;
        }
        if constexpr (MODE != 2) {
          float4 bv = *reinterpret_cast<const float4*>(&g.bias[br][m]);
          rv[0] += bv.x; rv[1] += bv.y; rv[2] += bv.z; rv[3] += bv.w;
        }
        if constexpr (MODE == 2) {
          float sc = g.rscale[br];
          us4 rr = *reinterpret_cast<const us4*>(&g.res[br][(size_t)n * 128 + m]);
#pragma unroll
          for (int r = 0; r < 4; ++r) rv[r] += sc * bf2f(rr[r]);
        }
        if constexpr (MODE == 3 || MODE == 4) {
          float sc = g.rscale[br];
          us4 gv = *reinterpret_cast<const us4*>(&g.G[(bq + n) * 256 + m]);
          us4 pv = *reinterpret_cast<const us4*>(&g.PET[(size_t)n * 256 + m]);
#pragma unroll
          for (int r = 0; r < 4; ++r) rv[r] += 2.f * bf2f(gv[r]) + sc * bf2f(pv[r]);
        }
        if constexpr (MODE == 4) {
          float a = g.afin[b];
          us4 ov = *reinterpret_cast<const us4*>(&g.other[(bq + n) * 256 + m]);
#pragma unroll
          for (int r = 0; r < 4; ++r) rv[r] = a * bf2f(ov[r]) + (1.f - a) * rv[r];
        }
        us4 pk;
#pragma unroll
        for (int r = 0; r < 4; ++r) pk[r] = f2bf(rv[r]);
        *reinterpret_cast<us4*>(&o16[(bq + n) * g.ldm + m]) = pk;
      }
    }
  }
}

// ---------------- alpha gate ----------------
__global__ __launch_bounds__(256) void k_alpha(const unsigned short* __restrict__ G,
                                               const float* __restrict__ w1,
                                               const float* __restrict__ b1,
                                               const float* __restrict__ w2,
                                               const float* __restrict__ b2,
                                               float* __restrict__ partial) {
  int b = blockIdx.y;
  int qbase = blockIdx.x * 16;
  __shared__ float gs[16][256];
  __shared__ float wsum[4];
  int t = threadIdx.x;
  const unsigned short* gp = G + ((size_t)b * NQ + qbase) * 256;
#pragma unroll
  for (int i = t; i < 512; i += 256) {
    bfrag8 v = *reinterpret_cast<const bfrag8*>(&gp[i * 8]);
    int row = i >> 5, col = (i & 31) * 8;
#pragma unroll
    for (int j = 0; j < 8; ++j) gs[row][col + j] = bf2f((unsigned short)v[j]);
  }
  __syncthreads();
  int wv = t >> 6, lane = t & 63;
  float a0 = 0.f, a1 = 0.f, a2 = 0.f, a3 = 0.f;
  const float* g0 = gs[wv * 4 + 0];
  const float* g1 = gs[wv * 4 + 1];
  const float* g2 = gs[wv * 4 + 2];
  const float* g3 = gs[wv * 4 + 3];
#pragma unroll 4
  for (int k = 0; k < 256; ++k) {
    float wk = w1[k * 64 + lane];
    a0 = fmaf(g0[k], wk, a0); a1 = fmaf(g1[k], wk, a1);
    a2 = fmaf(g2[k], wk, a2); a3 = fmaf(g3[k], wk, a3);
  }
  float b1l = b1[lane], w2l = w2[lane];
  a0 = fmaxf(a0 + b1l, 0.f) * w2l; a1 = fmaxf(a1 + b1l, 0.f) * w2l;
  a2 = fmaxf(a2 + b1l, 0.f) * w2l; a3 = fmaxf(a3 + b1l, 0.f) * w2l;
#pragma unroll
  for (int off = 32; off; off >>= 1) {
    a0 += __shfl_xor(a0, off); a1 += __shfl_xor(a1, off);
    a2 += __shfl_xor(a2, off); a3 += __shfl_xor(a3, off);
  }
  if (lane == 0) {
    float bb = b2[0];
    float s = 1.f / (1.f + expf(-(a0 + bb))) + 1.f / (1.f + expf(-(a1 + bb))) +
              1.f / (1.f + expf(-(a2 + bb))) + 1.f / (1.f + expf(-(a3 + bb)));
    wsum[wv] = s;
  }
  __syncthreads();
  if (t == 0) partial[(size_t)b * 256 + blockIdx.x] = wsum[0] + wsum[1] + wsum[2] + wsum[3];
}

__global__ __launch_bounds__(256) void k_alpha_fin(const float* __restrict__ partial,
                                                   float* __restrict__ afin,
                                                   float* __restrict__ out_a) {
  int b = blockIdx.x;
  __shared__ float sm[256];
  sm[threadIdx.x] = partial[(size_t)b * 256 + threadIdx.x];
  __syncthreads();
  for (int st = 128; st; st >>= 1) {
    if (threadIdx.x < st) sm[threadIdx.x] += sm[threadIdx.x + st];
    __syncthreads();
  }
  if (threadIdx.x == 0) {
    float a = sm[0] * (1.f / 4096.f);
    afin[b] = a;
    out_a[b] = a;
  }
}

// ---------------- deformable bilinear sampling, vectorized 8ch/thread ----------------
// block: 8 queries; thread t: qi=t>>5, head=(t&31)>>2, hdg=t&3 (8 channels)
__global__ __launch_bounds__(256) void k_sample(const unsigned short* __restrict__ VP0,
                                                const unsigned short* __restrict__ VP1,
                                                const unsigned short* __restrict__ SWb,
                                                unsigned short* __restrict__ OATT0,
                                                unsigned short* __restrict__ OATT1) {
  int y = blockIdx.y;
  int b = y & 7, br = y >> 3;
  int q0 = blockIdx.x * 8;
  const unsigned short* VP = (br ? VP1 : VP0) + (size_t)b * NQ * 256;
  const unsigned short* SWp = SWb + (((size_t)br * NB + b) * NQ + q0) * 128;
  unsigned short* OATT = (br ? OATT1 : OATT0) + ((size_t)b * NQ + q0) * 256;
  __shared__ unsigned short sws[1024];
  int t = threadIdx.x;
  *reinterpret_cast<us4*>(&sws[t * 4]) = *reinterpret_cast<const us4*>(&SWp[t * 4]);
  __syncthreads();
  int qi = t >> 5, ss = t & 31, head = ss >> 2, hdg = ss & 3;
  int q = q0 + qi;
  const unsigned short* sw = &sws[qi * 128];
  float l0 = bf2f(sw[64 + head * 4 + 0]);
  float l1 = bf2f(sw[64 + head * 4 + 1]);
  float l2 = bf2f(sw[64 + head * 4 + 2]);
  float l3 = bf2f(sw[64 + head * 4 + 3]);
  float mx = fmaxf(fmaxf(l0, l1), fmaxf(l2, l3));
  float e0 = expf(l0 - mx), e1 = expf(l1 - mx), e2 = expf(l2 - mx), e3 = expf(l3 - mx);
  float inv = 1.f / (e0 + e1 + e2 + e3);
  float aw[4] = {e0 * inv, e1 * inv, e2 * inv, e3 * inv};
  float rpx = (float)(q & 63) * (64.f / 63.f) - 0.5f;
  float rpy = (float)(q >> 6) * (64.f / 63.f) - 0.5f;
  const unsigned short* vb = VP + head * 32 + hdg * 8;
  float acc[8] = {};
#pragma unroll
  for (int p = 0; p < 4; ++p) {
    float px = rpx + bf2f(sw[head * 8 + p * 2 + 0]);
    float py = rpy + bf2f(sw[head * 8 + p * 2 + 1]);
    float fx = floorf(px), fy = floorf(py);
    int x0 = (int)fx, y0 = (int)fy;
    float wx = px - fx, wy = py - fy;
#pragma unroll
    for (int dy = 0; dy < 2; ++dy) {
#pragma unroll
      for (int dx = 0; dx < 2; ++dx) {
        int xi = x0 + dx, yi = y0 + dy;
        if (xi >= 0 && xi < 64 && yi >= 0 && yi < 64) {
          float wa = aw[p] * (dx ? wx : 1.f - wx) * (dy ? wy : 1.f - wy);
          bfrag8 v = *reinterpret_cast<const bfrag8*>(&vb[(size_t)(yi * 64 + xi) * 256]);
#pragma unroll
          for (int j = 0; j < 8; ++j) acc[j] = fmaf(wa, bf2f((unsigned short)v[j]), acc[j]);
        }
      }
    }
  }
  us8 o;
#pragma unroll
  for (int j = 0; j < 8; ++j) o[j] = f2bf(acc[j]);
  *reinterpret_cast<us8*>(&OATT[qi * 256 + ss * 8]) = o;
}

extern "C" void kernel_launch(void* const* d_in, const int* in_sizes, int n_in,
                              void* d_out, int out_size, void* d_ws, size_t ws_size,
                              hipStream_t stream) {
  const float* ground = (const float*)d_in[0];
  const float* sat = (const float*)d_in[1];
  const float* osm = (const float*)d_in[2];
  const float* gc_w = (const float*)d_in[3];
  const float* gc_b = (const float*)d_in[4];
  const float* sc_w = (const float*)d_in[5];
  const float* sc_b = (const float*)d_in[6];
  const float* up_w = (const float*)d_in[7];
  const float* up_b = (const float*)d_in[8];
  const float* a_w1 = (const float*)d_in[9];
  const float* a_b1 = (const float*)d_in[10];
  const float* a_w2 = (const float*)d_in[11];
  const float* a_b2 = (const float*)d_in[12];
  const float* vp_w[2] = {(const float*)d_in[13], (const float*)d_in[21]};
  const float* vp_b[2] = {(const float*)d_in[14], (const float*)d_in[22]};
  const float* so_w[2] = {(const float*)d_in[15], (const float*)d_in[23]};
  const float* so_b[2] = {(const float*)d_in[16], (const float*)d_in[24]};
  const float* aw_w[2] = {(const float*)d_in[17], (const float*)d_in[25]};
  const float* aw_b[2] = {(const float*)d_in[18], (const float*)d_in[26]};
  const float* op_w[2] = {(const float*)d_in[19], (const float*)d_in[27]};
  const float* op_b[2] = {(const float*)d_in[20], (const float*)d_in[28]};

  char* wsb = (char*)d_ws;
  const size_t MBy = 1 << 20;
  unsigned short* PET  = (unsigned short*)(wsb);                 // 2 MB
  unsigned short* WG   = (unsigned short*)(wsb + 2 * MBy);       // 512 KB
  unsigned short* WV0  = (unsigned short*)(wsb + 2 * MBy + 524288);   // 160 KB
  unsigned short* WV1  = (unsigned short*)(wsb + 2 * MBy + 786432);   // 160 KB
  unsigned short* WUP  = (unsigned short*)(wsb + 3 * MBy);            // 192 KB
  unsigned short* OPT0 = (unsigned short*)(wsb + 3 * MBy + 262144);   // 128 KB
  unsigned short* OPT1 = (unsigned short*)(wsb + 3 * MBy + 393216);   // 128 KB
  unsigned short* SOW0 = (unsigned short*)(wsb + 3 * MBy + 524288);   // 64 KB
  unsigned short* SOW1 = (unsigned short*)(wsb + 3 * MBy + 589824);   // 64 KB
  unsigned short* PESO0 = (unsigned short*)(wsb + 4 * MBy);           // 1 MB
  unsigned short* PESO1 = (unsigned short*)(wsb + 5 * MBy);           // 1 MB
  float* SOB0 = (float*)(wsb + 6 * MBy);
  float* SOB1 = (float*)(wsb + 6 * MBy + 1024);
  float* BV0  = (float*)(wsb + 6 * MBy + 2048);
  float* BV1  = (float*)(wsb + 6 * MBy + 4096);
  float* BUPP = (float*)(wsb + 6 * MBy + 8192);
  float* PART = (float*)(wsb + 6 * MBy + 16384);  // 8 KB
  float* AFIN = (float*)(wsb + 6 * MBy + 32768);
  unsigned short* G     = (unsigned short*)(wsb + 8 * MBy);    // 16 MB
  unsigned short* XS    = (unsigned short*)(wsb + 24 * MBy);   // 20 MB ; OATT1 alias
  unsigned short* XO    = (unsigned short*)(wsb + 44 * MBy);   // 20 MB ; SATO alias
  unsigned short* VP0b  = (unsigned short*)(wsb + 64 * MBy);   // 16 MB
  unsigned short* VP1b  = (unsigned short*)(wsb + 80 * MBy);   // 16 MB
  unsigned short* SW    = (unsigned short*)(wsb + 96 * MBy);   // 16 MB [2][B][Q][128]
  unsigned short* OATT0 = (unsigned short*)(wsb + 112 * MBy);  // 16 MB ; FUSED alias
  unsigned short* XG    = (unsigned short*)(wsb + 64 * MBy);   // 64 MB transient (over VP0,VP1,SW,OATT0)
  unsigned short* OATT1 = XS;
  unsigned short* SATO  = XO;
  unsigned short* FUSED = OATT0;

  float* out32 = (float*)d_out;
  float* out_a = out32 + (size_t)NB * 320 * NQ;

  dim3 blk(256);
  // ---- prep ----
  pe_kernel<<<dim3(4096), blk, 0, stream>>>(PET);
  k_cvt<<<dim3(1024), blk, 0, stream>>>(gc_w, WG, 262144);
  k_wcomb<<<dim3(256, 2), dim3(320), 0, stream>>>(vp_w[0], vp_w[1], sc_w, WV0, WV1);
  k_wcombb<<<dim3(2), blk, 0, stream>>>(vp_w[0], vp_b[0], vp_w[1], vp_b[1], sc_b, BV0, BV1);
  k_wup<<<dim3(384), blk, 0, stream>>>(up_w, WUP);
  k_bup<<<dim3(2), blk, 0, stream>>>(up_b, BUPP);
  k_wtrans<<<dim3(256), blk, 0, stream>>>(op_w[0], OPT0);
  k_wtrans<<<dim3(256), blk, 0, stream>>>(op_w[1], OPT1);
  k_soaw<<<dim3(128), blk, 0, stream>>>(so_w[0], so_b[0], aw_w[0], aw_b[0], SOW0, SOB0);
  k_soaw<<<dim3(128), blk, 0, stream>>>(so_w[1], so_b[1], aw_w[1], aw_b[1], SOW1, SOB1);

  // ---- PESO_br = s_br*(PE @ soaw_w_br) + bias_br : [4096][128] bf16 ----
  {
    GArgs a = {};
    a.W[0] = SOW0; a.W[1] = SOW1;
    a.X[0] = PET;  a.X[1] = PET;
    a.bias[0] = SOB0; a.bias[1] = SOB1;
    a.out[0] = PESO0; a.out[1] = PESO1;
    a.rscale[0] = 1.f; a.rscale[1] = 2.f;
    a.K = 256; a.ldm = 128; a.bmask = 0; a.brshift = 0;
    gemm_bf16<1><<<dim3(32, 1, 2), blk, 0, stream>>>(a);
  }

  // ---- ground transpose + gconv ----
  k_transpose<<<dim3(128, 16, NB), blk, 0, stream>>>(ground, XG, 1024);
  {
    GArgs a = {};
    a.W[0] = WG; a.W[1] = WG; a.X[0] = XG; a.X[1] = XG;
    a.bias[0] = gc_b; a.bias[1] = gc_b;
    a.out[0] = G; a.out[1] = G;
    a.K = 1024; a.ldm = 256; a.bmask = 7; a.brshift = 31;
    gemm_bf16<0><<<dim3(32, 2, NB), blk, 0, stream>>>(a);
  }

  // ---- alpha ----
  k_alpha<<<dim3(256, NB), blk, 0, stream>>>(G, a_w1, a_b1, a_w2, a_b2, PART);
  k_alpha_fin<<<dim3(NB), blk, 0, stream>>>(PART, AFIN, out_a);

  // ---- sat/osm transposes (XG dead after gconv) ----
  k_transpose<<<dim3(128, 5, NB), blk, 0, stream>>>(sat, XS, 320);
  k_transpose<<<dim3(128, 5, NB), blk, 0, stream>>>(osm, XO, 320);

  // ---- SW_br = G @ soaw_w_br + PESO_br  (both branches, z=16) ----
  {
    GArgs a = {};
    a.W[0] = SOW0; a.W[1] = SOW1;
    a.X[0] = G; a.X[1] = G;
    a.out[0] = SW; a.out[1] = SW + (size_t)NB * NQ * 128;
    a.res[0] = PESO0; a.res[1] = PESO1;
    a.rscale[0] = 1.f; a.rscale[1] = 1.f;
    a.K = 256; a.ldm = 128; a.bmask = 7; a.brshift = 3;
    gemm_bf16<2><<<dim3(32, 1, 16), blk, 0, stream>>>(a);
  }

  // ---- VP_br = X_br @ WV_br + BV_br (combined conv+proj, both branches) ----
  {
    GArgs a = {};
    a.W[0] = WV0; a.W[1] = WV1;
    a.X[0] = XS; a.X[1] = XO;
    a.bias[0] = BV0; a.bias[1] = BV1;
    a.out[0] = VP0b; a.out[1] = VP1b;
    a.K = 320; a.ldm = 256; a.bmask = 7; a.brshift = 3;
    gemm_bf16<0><<<dim3(32, 2, 16), blk, 0, stream>>>(a);
  }

  // ---- sampling (both branches) ----
  k_sample<<<dim3(512, 16), blk, 0, stream>>>(VP0b, VP1b, SW, OATT0, OATT1);

  // ---- output proj br0 -> SATO ----
  {
    GArgs a = {};
    a.W[0] = OPT0; a.W[1] = OPT0;
    a.X[0] = OATT0; a.X[1] = OATT0;
    a.bias[0] = op_b[0]; a.bias[1] = op_b[0];
    a.out[0] = SATO; a.out[1] = SATO;
    a.rscale[0] = 2.f; a.rscale[1] = 2.f;
    a.G = G; a.PET = PET;
    a.K = 256; a.ldm = 256; a.bmask = 7; a.brshift = 31;
    gemm_bf16<3><<<dim3(32, 2, NB), blk, 0, stream>>>(a);
  }
  // ---- output proj br1 + blend -> FUSED ----
  {
    GArgs a = {};
    a.W[0] = OPT1; a.W[1] = OPT1;
    a.X[0] = OATT1; a.X[1] = OATT1;
    a.bias[0] = op_b[1]; a.bias[1] = op_b[1];
    a.out[0] = FUSED; a.out[1] = FUSED;
    a.rscale[0] = 4.f; a.rscale[1] = 4.f;
    a.G = G; a.PET = PET;
    a.other = SATO; a.afin = AFIN;
    a.K = 256; a.ldm = 256; a.bmask = 7; a.brshift = 31;
    gemm_bf16<4><<<dim3(32, 2, NB), blk, 0, stream>>>(a);
  }
  // ---- up conv -> f32 out ----
  {
    GArgs a = {};
    a.W[0] = WUP; a.W[1] = WUP;
    a.X[0] = FUSED; a.X[1] = FUSED;
    a.bias[0] = BUPP; a.bias[1] = BUPP;
    a.out[0] = out32; a.out[1] = out32;
    a.K = 256; a.ldm = 0; a.Mreal = 320; a.bmask = 7; a.brshift = 31;
    gemm_bf16<5><<<dim3(32, 3, NB), blk, 0, stream>>>(a);
  }
}

// Round 5
// 333.291 us; speedup vs baseline: 3.5616x; 1.0019x over previous
//
#include <hip/hip_runtime.h>
#include <cstddef>
#include <cstdint>

#define NB 8
#define NQ 4096

typedef __attribute__((ext_vector_type(8))) short bfrag8;
typedef __attribute__((ext_vector_type(4))) float facc4;
typedef __attribute__((ext_vector_type(4))) unsigned short us4;
typedef __attribute__((ext_vector_type(8))) unsigned short us8;

__device__ __forceinline__ float bf2f(unsigned short u) {
  union { unsigned int i; float f; } v; v.i = ((unsigned int)u) << 16; return v.f;
}
__device__ __forceinline__ unsigned short f2bf(float f) {
  union { float f; unsigned int i; } v; v.f = f;
  unsigned int r = v.i + 0x7FFFu + ((v.i >> 16) & 1u);
  return (unsigned short)(r >> 16);
}
__device__ __forceinline__ void gload16(const void* g, void* l) {
  __builtin_amdgcn_global_load_lds(
      (const __attribute__((address_space(1))) void*)g,
      (__attribute__((address_space(3))) void*)l, 16, 0, 0);
}

// ---------------- weight prep ----------------
__global__ __launch_bounds__(256) void k_cvt(const float* __restrict__ s,
                                             unsigned short* __restrict__ d, int n) {
  int i = blockIdx.x * 256 + threadIdx.x;
  if (i < n) d[i] = f2bf(s[i]);
}
// combined value weights: WV[m][k] = sum_c vp_w[c][m] * sc_w[c][k]  (m<256, k<320)
__global__ __launch_bounds__(320) void k_wcomb(const float* __restrict__ vp_w0,
                                               const float* __restrict__ vp_w1,
                                               const float* __restrict__ sc_w,
                                               unsigned short* __restrict__ WV0,
                                               unsigned short* __restrict__ WV1) {
  int m = blockIdx.x, br = blockIdx.y, k = threadIdx.x;
  const float* vp = br ? vp_w1 : vp_w0;
  float acc = 0.f;
  for (int c = 0; c < 256; ++c)
    acc = fmaf(vp[c * 256 + m], sc_w[c * 320 + k], acc);
  (br ? WV1 : WV0)[m * 320 + k] = f2bf(acc);
}
// combined value bias: BV[m] = vp_b[m] + sum_c sc_b[c]*vp_w[c][m]
__global__ __launch_bounds__(256) void k_wcombb(const float* __restrict__ vp_w0,
                                                const float* __restrict__ vp_b0,
                                                const float* __restrict__ vp_w1,
                                                const float* __restrict__ vp_b1,
                                                const float* __restrict__ sc_b,
                                                float* __restrict__ BV0,
                                                float* __restrict__ BV1) {
  int m = threadIdx.x, br = blockIdx.x;
  const float* vp = br ? vp_w1 : vp_w0;
  float acc = (br ? vp_b1 : vp_b0)[m];
  for (int c = 0; c < 256; ++c) acc = fmaf(sc_b[c], vp[c * 256 + m], acc);
  (br ? BV1 : BV0)[m] = acc;
}
// up_w [320][256] -> [384][256] bf16 zero-padded
__global__ __launch_bounds__(256) void k_wup(const float* __restrict__ s,
                                             unsigned short* __restrict__ d) {
  int i = blockIdx.x * 256 + threadIdx.x;
  int m = i >> 8, k = i & 255;
  d[i] = (m < 320) ? f2bf(s[m * 256 + k]) : 0;
}
// op_w [k][o] 256x256 -> [o][k] bf16
__global__ __launch_bounds__(256) void k_wtrans(const float* __restrict__ s,
                                                unsigned short* __restrict__ d) {
  int i = blockIdx.x * 256 + threadIdx.x;
  int o = i >> 8, k = i & 255;
  d[i] = f2bf(s[(k << 8) + o]);
}
// so_w [256][64], aw_w [256][32] -> W[128][256] + bias[128]
__global__ __launch_bounds__(256) void k_soaw(const float* __restrict__ so_w,
                                              const float* __restrict__ so_b,
                                              const float* __restrict__ aw_w,
                                              const float* __restrict__ aw_b,
                                              unsigned short* __restrict__ W,
                                              float* __restrict__ Bb) {
  int i = blockIdx.x * 256 + threadIdx.x;
  int row = i >> 8, k = i & 255;
  float v = 0.f;
  if (row < 64) v = so_w[k * 64 + row];
  else if (row < 96) v = aw_w[k * 32 + (row - 64)];
  W[i] = f2bf(v);
  if (i < 128) Bb[i] = (i < 64) ? so_b[i] : ((i < 96) ? aw_b[i - 64] : 0.f);
}
__global__ __launch_bounds__(256) void k_bup(const float* __restrict__ s, float* __restrict__ d) {
  int i = blockIdx.x * 256 + threadIdx.x;
  if (i < 384) d[i] = (i < 320) ? s[i] : 0.f;
}

// ---------------- PE table bf16 [Q][256] ----------------
__global__ __launch_bounds__(256) void pe_kernel(unsigned short* __restrict__ pe) {
  int idx = blockIdx.x * 256 + threadIdx.x;
  int q = idx >> 8, c = idx & 255;
  int h = q >> 6, w = q & 63;
  int k = c >> 2, m = c & 3;
  float dv = expf((float)(2 * k) * (-9.210340371976184f / 128.0f));
  float arg = ((m < 2) ? (float)w : (float)h) * dv;
  pe[idx] = f2bf(((m & 1) == 0) ? sinf(arg) : cosf(arg));
}

// ---------------- transpose: [B][K][4096] f32 -> [B][4096][K] bf16, 64k x 32q tiles
__global__ __launch_bounds__(256) void k_transpose(const float* __restrict__ src,
                                                   unsigned short* __restrict__ dst, int K) {
  int b = blockIdx.z;
  int k0 = blockIdx.y * 64, n0 = blockIdx.x * 32;
  const float* s = src + (size_t)b * K * NQ;
  unsigned short* d = dst + (size_t)b * NQ * K;
  __shared__ float tile[64][33];
  int t = threadIdx.x;
  int r = t >> 2, c8 = (t & 3) * 8;
  float4 v0 = *reinterpret_cast<const float4*>(&s[(size_t)(k0 + r) * NQ + n0 + c8]);
  float4 v1 = *reinterpret_cast<const float4*>(&s[(size_t)(k0 + r) * NQ + n0 + c8 + 4]);
  tile[r][c8 + 0] = v0.x; tile[r][c8 + 1] = v0.y; tile[r][c8 + 2] = v0.z; tile[r][c8 + 3] = v0.w;
  tile[r][c8 + 4] = v1.x; tile[r][c8 + 5] = v1.y; tile[r][c8 + 6] = v1.z; tile[r][c8 + 7] = v1.w;
  __syncthreads();
  int qr = t >> 3, kg = (t & 7) * 8;
  us8 pk;
#pragma unroll
  for (int j = 0; j < 8; ++j) pk[j] = f2bf(tile[kg + j][qr]);
  *reinterpret_cast<us8*>(&d[(size_t)(n0 + qr) * K + k0 + kg]) = pk;
}

// ---------------- unified bf16 MFMA GEMM ----------------
struct GArgs {
  const unsigned short* W[2];
  const unsigned short* X[2];
  const float* bias[2];
  void* out[2];
  const unsigned short* res[2]; // [4096][128] broadcast residual (MODE 2)
  float rscale[2];              // MODE1: acc scale; MODE2: res scale; MODE3/4: PET scale
  const unsigned short* G;      // MODE3/4 residual (per-batch [N][256])
  const unsigned short* PET;    // MODE3/4 broadcast residual [N][256]
  const unsigned short* other;  // MODE4 blend
  const float* afin;            // MODE4 blend
  int K, ldm, Mreal, bmask, brshift;
};
// MODE 0: out = acc + bias (bf16)
// MODE 1: out = rscale*acc + bias (bf16)
// MODE 2: out = acc + rscale*res[n*128+m] (bf16)
// MODE 3: out = acc + bias + 2*G + rscale*PET (bf16)
// MODE 4: out = a*other + (1-a)*(acc + bias + 2*G + rscale*PET) (bf16)
// MODE 5: out f32 [B][Mreal][4096] = acc + bias
template <int MODE>
__global__ __launch_bounds__(256) void gemm_bf16(GArgs g) {
  __shared__ unsigned short As[8192]; // [128][64] swizzled
  __shared__ unsigned short Bs[8192];
  const int t = threadIdx.x;
  const int lane = t & 63, w = t >> 6;
  const int z = blockIdx.z;
  const int b = z & g.bmask, br = z >> g.brshift;
  const int K = g.K;
  const int n0 = blockIdx.x * 128, m0 = blockIdx.y * 128;
  const unsigned short* W = g.W[br];
  const unsigned short* Xb = g.X[br] + (size_t)b * NQ * K;

  const unsigned short* asrc[4];
  const unsigned short* bsrc[4];
  unsigned short* adst[4];
  unsigned short* bdst[4];
#pragma unroll
  for (int i = 0; i < 4; ++i) {
    int cid = i * 256 + t;
    int row = cid >> 3;
    int cc = (cid & 7) ^ (row & 7);
    asrc[i] = W + (size_t)(m0 + row) * K + cc * 8;
    bsrc[i] = Xb + (size_t)(n0 + row) * K + cc * 8;
    adst[i] = &As[i * 2048 + w * 512];
    bdst[i] = &Bs[i * 2048 + w * 512];
  }

  const int wm = (w >> 1) * 64, wn = (w & 1) * 64;
  const int l15 = lane & 15, l4 = lane >> 4;
  facc4 acc[4][4];
#pragma unroll
  for (int i = 0; i < 4; ++i)
#pragma unroll
    for (int j = 0; j < 4; ++j) acc[i][j] = facc4{0.f, 0.f, 0.f, 0.f};

  for (int k0 = 0; k0 < K; k0 += 64) {
    if (k0) __syncthreads();
#pragma unroll
    for (int i = 0; i < 4; ++i) {
      gload16(asrc[i], adst[i]);
      gload16(bsrc[i], bdst[i]);
      asrc[i] += 64; bsrc[i] += 64;
    }
    __syncthreads();
#pragma unroll
    for (int kk = 0; kk < 2; ++kk) {
      bfrag8 af[4], bf[4];
#pragma unroll
      for (int mi = 0; mi < 4; ++mi) {
        int row = wm + mi * 16 + l15;
        af[mi] = *reinterpret_cast<const bfrag8*>(
            &As[row * 64 + (((kk * 4 + l4) ^ (row & 7)) * 8)]);
      }
#pragma unroll
      for (int ni = 0; ni < 4; ++ni) {
        int row = wn + ni * 16 + l15;
        bf[ni] = *reinterpret_cast<const bfrag8*>(
            &Bs[row * 64 + (((kk * 4 + l4) ^ (row & 7)) * 8)]);
      }
#pragma unroll
      for (int mi = 0; mi < 4; ++mi)
#pragma unroll
        for (int ni = 0; ni < 4; ++ni)
          acc[mi][ni] = __builtin_amdgcn_mfma_f32_16x16x32_bf16(af[mi], bf[ni], acc[mi][ni], 0, 0, 0);
    }
  }

  const size_t bq = (size_t)b * NQ;
#pragma unroll
  for (int mi = 0; mi < 4; ++mi) {
#pragma unroll
    for (int ni = 0; ni < 4; ++ni) {
      int m = m0 + wm + mi * 16 + l4 * 4;
      int n = n0 + wn + ni * 16 + l15;
      facc4 v = acc[mi][ni];
      if constexpr (MODE == 5) {
        float* o32 = (float*)g.out[br];
#pragma unroll
        for (int r = 0; r < 4; ++r)
          if (m + r < g.Mreal)
            o32[((size_t)b * g.Mreal + (m + r)) * NQ + n] = v[r] + g.bias[br][m + r];
      } else {
        unsigned short* o16 = (unsigned short*)g.out[br];
        float rv[4] = {v[0], v[1], v[2], v[3]};
        if constexpr (MODE == 1) {
          float sc = g.rscale[br];
#pragma unroll
          for (int r = 0; r < 4; ++r) rv[r] *= sc;
        }
        if constexpr (MODE != 2) {
          float4 bv = *reinterpret_cast<const float4*>(&g.bias[br][m]);
          rv[0] += bv.x; rv[1] += bv.y; rv[2] += bv.z; rv[3] += bv.w;
        }
        if constexpr (MODE == 2) {
          float sc = g.rscale[br];
          us4 rr = *reinterpret_cast<const us4*>(&g.res[br][(size_t)n * 128 + m]);
#pragma unroll
          for (int r = 0; r < 4; ++r) rv[r] += sc * bf2f(rr[r]);
        }
        if constexpr (MODE == 3 || MODE == 4) {
          float sc = g.rscale[br];
          us4 gv = *reinterpret_cast<const us4*>(&g.G[(bq + n) * 256 + m]);
          us4 pv = *reinterpret_cast<const us4*>(&g.PET[(size_t)n * 256 + m]);
#pragma unroll
          for (int r = 0; r < 4; ++r) rv[r] += 2.f * bf2f(gv[r]) + sc * bf2f(pv[r]);
        }
        if constexpr (MODE == 4) {
          float a = g.afin[b];
          us4 ov = *reinterpret_cast<const us4*>(&g.other[(bq + n) * 256 + m]);
#pragma unroll
          for (int r = 0; r < 4; ++r) rv[r] = a * bf2f(ov[r]) + (1.f - a) * rv[r];
        }
        us4 pk;
#pragma unroll
        for (int r = 0; r < 4; ++r) pk[r] = f2bf(rv[r]);
        *reinterpret_cast<us4*>(&o16[(bq + n) * g.ldm + m]) = pk;
      }
    }
  }
}

// ---------------- alpha gate ----------------
__global__ __launch_bounds__(256) void k_alpha(const unsigned short* __restrict__ G,
                                               const float* __restrict__ w1,
                                               const float* __restrict__ b1,
                                               const float* __restrict__ w2,
                                               const float* __restrict__ b2,
                                               float* __restrict__ partial) {
  int b = blockIdx.y;
  int qbase = blockIdx.x * 16;
  __shared__ float gs[16][256];
  __shared__ float wsum[4];
  int t = threadIdx.x;
  const unsigned short* gp = G + ((size_t)b * NQ + qbase) * 256;
#pragma unroll
  for (int i = t; i < 512; i += 256) {
    bfrag8 v = *reinterpret_cast<const bfrag8*>(&gp[i * 8]);
    int row = i >> 5, col = (i & 31) * 8;
#pragma unroll
    for (int j = 0; j < 8; ++j) gs[row][col + j] = bf2f((unsigned short)v[j]);
  }
  __syncthreads();
  int wv = t >> 6, lane = t & 63;
  float a0 = 0.f, a1 = 0.f, a2 = 0.f, a3 = 0.f;
  const float* g0 = gs[wv * 4 + 0];
  const float* g1 = gs[wv * 4 + 1];
  const float* g2 = gs[wv * 4 + 2];
  const float* g3 = gs[wv * 4 + 3];
#pragma unroll 4
  for (int k = 0; k < 256; ++k) {
    float wk = w1[k * 64 + lane];
    a0 = fmaf(g0[k], wk, a0); a1 = fmaf(g1[k], wk, a1);
    a2 = fmaf(g2[k], wk, a2); a3 = fmaf(g3[k], wk, a3);
  }
  float b1l = b1[lane], w2l = w2[lane];
  a0 = fmaxf(a0 + b1l, 0.f) * w2l; a1 = fmaxf(a1 + b1l, 0.f) * w2l;
  a2 = fmaxf(a2 + b1l, 0.f) * w2l; a3 = fmaxf(a3 + b1l, 0.f) * w2l;
#pragma unroll
  for (int off = 32; off; off >>= 1) {
    a0 += __shfl_xor(a0, off); a1 += __shfl_xor(a1, off);
    a2 += __shfl_xor(a2, off); a3 += __shfl_xor(a3, off);
  }
  if (lane == 0) {
    float bb = b2[0];
    float s = 1.f / (1.f + expf(-(a0 + bb))) + 1.f / (1.f + expf(-(a1 + bb))) +
              1.f / (1.f + expf(-(a2 + bb))) + 1.f / (1.f + expf(-(a3 + bb)));
    wsum[wv] = s;
  }
  __syncthreads();
  if (t == 0) partial[(size_t)b * 256 + blockIdx.x] = wsum[0] + wsum[1] + wsum[2] + wsum[3];
}

__global__ __launch_bounds__(256) void k_alpha_fin(const float* __restrict__ partial,
                                                   float* __restrict__ afin,
                                                   float* __restrict__ out_a) {
  int b = blockIdx.x;
  __shared__ float sm[256];
  sm[threadIdx.x] = partial[(size_t)b * 256 + threadIdx.x];
  __syncthreads();
  for (int st = 128; st; st >>= 1) {
    if (threadIdx.x < st) sm[threadIdx.x] += sm[threadIdx.x + st];
    __syncthreads();
  }
  if (threadIdx.x == 0) {
    float a = sm[0] * (1.f / 4096.f);
    afin[b] = a;
    out_a[b] = a;
  }
}

// ---------------- deformable bilinear sampling, vectorized 8ch/thread ----------------
// block: 8 queries; thread t: qi=t>>5, head=(t&31)>>2, hdg=t&3 (8 channels)
__global__ __launch_bounds__(256) void k_sample(const unsigned short* __restrict__ VP0,
                                                const unsigned short* __restrict__ VP1,
                                                const unsigned short* __restrict__ SWb,
                                                unsigned short* __restrict__ OATT0,
                                                unsigned short* __restrict__ OATT1) {
  int y = blockIdx.y;
  int b = y & 7, br = y >> 3;
  int q0 = blockIdx.x * 8;
  const unsigned short* VP = (br ? VP1 : VP0) + (size_t)b * NQ * 256;
  const unsigned short* SWp = SWb + (((size_t)br * NB + b) * NQ + q0) * 128;
  unsigned short* OATT = (br ? OATT1 : OATT0) + ((size_t)b * NQ + q0) * 256;
  __shared__ unsigned short sws[1024];
  int t = threadIdx.x;
  *reinterpret_cast<us4*>(&sws[t * 4]) = *reinterpret_cast<const us4*>(&SWp[t * 4]);
  __syncthreads();
  int qi = t >> 5, ss = t & 31, head = ss >> 2, hdg = ss & 3;
  int q = q0 + qi;
  const unsigned short* sw = &sws[qi * 128];
  float l0 = bf2f(sw[64 + head * 4 + 0]);
  float l1 = bf2f(sw[64 + head * 4 + 1]);
  float l2 = bf2f(sw[64 + head * 4 + 2]);
  float l3 = bf2f(sw[64 + head * 4 + 3]);
  float mx = fmaxf(fmaxf(l0, l1), fmaxf(l2, l3));
  float e0 = expf(l0 - mx), e1 = expf(l1 - mx), e2 = expf(l2 - mx), e3 = expf(l3 - mx);
  float inv = 1.f / (e0 + e1 + e2 + e3);
  float aw[4] = {e0 * inv, e1 * inv, e2 * inv, e3 * inv};
  float rpx = (float)(q & 63) * (64.f / 63.f) - 0.5f;
  float rpy = (float)(q >> 6) * (64.f / 63.f) - 0.5f;
  const unsigned short* vb = VP + head * 32 + hdg * 8;
  float acc[8] = {};
#pragma unroll
  for (int p = 0; p < 4; ++p) {
    float px = rpx + bf2f(sw[head * 8 + p * 2 + 0]);
    float py = rpy + bf2f(sw[head * 8 + p * 2 + 1]);
    float fx = floorf(px), fy = floorf(py);
    int x0 = (int)fx, y0 = (int)fy;
    float wx = px - fx, wy = py - fy;
#pragma unroll
    for (int dy = 0; dy < 2; ++dy) {
#pragma unroll
      for (int dx = 0; dx < 2; ++dx) {
        int xi = x0 + dx, yi = y0 + dy;
        if (xi >= 0 && xi < 64 && yi >= 0 && yi < 64) {
          float wa = aw[p] * (dx ? wx : 1.f - wx) * (dy ? wy : 1.f - wy);
          bfrag8 v = *reinterpret_cast<const bfrag8*>(&vb[(size_t)(yi * 64 + xi) * 256]);
#pragma unroll
          for (int j = 0; j < 8; ++j) acc[j] = fmaf(wa, bf2f((unsigned short)v[j]), acc[j]);
        }
      }
    }
  }
  us8 o;
#pragma unroll
  for (int j = 0; j < 8; ++j) o[j] = f2bf(acc[j]);
  *reinterpret_cast<us8*>(&OATT[qi * 256 + ss * 8]) = o;
}

extern "C" void kernel_launch(void* const* d_in, const int* in_sizes, int n_in,
                              void* d_out, int out_size, void* d_ws, size_t ws_size,
                              hipStream_t stream) {
  const float* ground = (const float*)d_in[0];
  const float* sat = (const float*)d_in[1];
  const float* osm = (const float*)d_in[2];
  const float* gc_w = (const float*)d_in[3];
  const float* gc_b = (const float*)d_in[4];
  const float* sc_w = (const float*)d_in[5];
  const float* sc_b = (const float*)d_in[6];
  const float* up_w = (const float*)d_in[7];
  const float* up_b = (const float*)d_in[8];
  const float* a_w1 = (const float*)d_in[9];
  const float* a_b1 = (const float*)d_in[10];
  const float* a_w2 = (const float*)d_in[11];
  const float* a_b2 = (const float*)d_in[12];
  const float* vp_w[2] = {(const float*)d_in[13], (const float*)d_in[21]};
  const float* vp_b[2] = {(const float*)d_in[14], (const float*)d_in[22]};
  const float* so_w[2] = {(const float*)d_in[15], (const float*)d_in[23]};
  const float* so_b[2] = {(const float*)d_in[16], (const float*)d_in[24]};
  const float* aw_w[2] = {(const float*)d_in[17], (const float*)d_in[25]};
  const float* aw_b[2] = {(const float*)d_in[18], (const float*)d_in[26]};
  const float* op_w[2] = {(const float*)d_in[19], (const float*)d_in[27]};
  const float* op_b[2] = {(const float*)d_in[20], (const float*)d_in[28]};

  char* wsb = (char*)d_ws;
  const size_t MBy = 1 << 20;
  unsigned short* PET  = (unsigned short*)(wsb);                 // 2 MB
  unsigned short* WG   = (unsigned short*)(wsb + 2 * MBy);       // 512 KB
  unsigned short* WV0  = (unsigned short*)(wsb + 2 * MBy + 524288);   // 160 KB
  unsigned short* WV1  = (unsigned short*)(wsb + 2 * MBy + 786432);   // 160 KB
  unsigned short* WUP  = (unsigned short*)(wsb + 3 * MBy);            // 192 KB
  unsigned short* OPT0 = (unsigned short*)(wsb + 3 * MBy + 262144);   // 128 KB
  unsigned short* OPT1 = (unsigned short*)(wsb + 3 * MBy + 393216);   // 128 KB
  unsigned short* SOW0 = (unsigned short*)(wsb + 3 * MBy + 524288);   // 64 KB
  unsigned short* SOW1 = (unsigned short*)(wsb + 3 * MBy + 589824);   // 64 KB
  unsigned short* PESO0 = (unsigned short*)(wsb + 4 * MBy);           // 1 MB
  unsigned short* PESO1 = (unsigned short*)(wsb + 5 * MBy);           // 1 MB
  float* SOB0 = (float*)(wsb + 6 * MBy);
  float* SOB1 = (float*)(wsb + 6 * MBy + 1024);
  float* BV0  = (float*)(wsb + 6 * MBy + 2048);
  float* BV1  = (float*)(wsb + 6 * MBy + 4096);
  float* BUPP = (float*)(wsb + 6 * MBy + 8192);
  float* PART = (float*)(wsb + 6 * MBy + 16384);  // 8 KB
  float* AFIN = (float*)(wsb + 6 * MBy + 32768);
  unsigned short* G     = (unsigned short*)(wsb + 8 * MBy);    // 16 MB
  unsigned short* XS    = (unsigned short*)(wsb + 24 * MBy);   // 20 MB ; OATT1 alias
  unsigned short* XO    = (unsigned short*)(wsb + 44 * MBy);   // 20 MB ; SATO alias
  unsigned short* VP0b  = (unsigned short*)(wsb + 64 * MBy);   // 16 MB
  unsigned short* VP1b  = (unsigned short*)(wsb + 80 * MBy);   // 16 MB
  unsigned short* SW    = (unsigned short*)(wsb + 96 * MBy);   // 16 MB [2][B][Q][128]
  unsigned short* OATT0 = (unsigned short*)(wsb + 112 * MBy);  // 16 MB ; FUSED alias
  unsigned short* XG    = (unsigned short*)(wsb + 64 * MBy);   // 64 MB transient (over VP0,VP1,SW,OATT0)
  unsigned short* OATT1 = XS;
  unsigned short* SATO  = XO;
  unsigned short* FUSED = OATT0;

  float* out32 = (float*)d_out;
  float* out_a = out32 + (size_t)NB * 320 * NQ;

  dim3 blk(256);
  // ---- prep ----
  pe_kernel<<<dim3(4096), blk, 0, stream>>>(PET);
  k_cvt<<<dim3(1024), blk, 0, stream>>>(gc_w, WG, 262144);
  k_wcomb<<<dim3(256, 2), dim3(320), 0, stream>>>(vp_w[0], vp_w[1], sc_w, WV0, WV1);
  k_wcombb<<<dim3(2), blk, 0, stream>>>(vp_w[0], vp_b[0], vp_w[1], vp_b[1], sc_b, BV0, BV1);
  k_wup<<<dim3(384), blk, 0, stream>>>(up_w, WUP);
  k_bup<<<dim3(2), blk, 0, stream>>>(up_b, BUPP);
  k_wtrans<<<dim3(256), blk, 0, stream>>>(op_w[0], OPT0);
  k_wtrans<<<dim3(256), blk, 0, stream>>>(op_w[1], OPT1);
  k_soaw<<<dim3(128), blk, 0, stream>>>(so_w[0], so_b[0], aw_w[0], aw_b[0], SOW0, SOB0);
  k_soaw<<<dim3(128), blk, 0, stream>>>(so_w[1], so_b[1], aw_w[1], aw_b[1], SOW1, SOB1);

  // ---- PESO_br = s_br*(PE @ soaw_w_br) + bias_br : [4096][128] bf16 ----
  {
    GArgs a = {};
    a.W[0] = SOW0; a.W[1] = SOW1;
    a.X[0] = PET;  a.X[1] = PET;
    a.bias[0] = SOB0; a.bias[1] = SOB1;
    a.out[0] = PESO0; a.out[1] = PESO1;
    a.rscale[0] = 1.f; a.rscale[1] = 2.f;
    a.K = 256; a.ldm = 128; a.bmask = 0; a.brshift = 0;
    gemm_bf16<1><<<dim3(32, 1, 2), blk, 0, stream>>>(a);
  }

  // ---- ground transpose + gconv ----
  k_transpose<<<dim3(128, 16, NB), blk, 0, stream>>>(ground, XG, 1024);
  {
    GArgs a = {};
    a.W[0] = WG; a.W[1] = WG; a.X[0] = XG; a.X[1] = XG;
    a.bias[0] = gc_b; a.bias[1] = gc_b;
    a.out[0] = G; a.out[1] = G;
    a.K = 1024; a.ldm = 256; a.bmask = 7; a.brshift = 31;
    gemm_bf16<0><<<dim3(32, 2, NB), blk, 0, stream>>>(a);
  }

  // ---- alpha ----
  k_alpha<<<dim3(256, NB), blk, 0, stream>>>(G, a_w1, a_b1, a_w2, a_b2, PART);
  k_alpha_fin<<<dim3(NB), blk, 0, stream>>>(PART, AFIN, out_a);

  // ---- sat/osm transposes (XG dead after gconv) ----
  k_transpose<<<dim3(128, 5, NB), blk, 0, stream>>>(sat, XS, 320);
  k_transpose<<<dim3(128, 5, NB), blk, 0, stream>>>(osm, XO, 320);

  // ---- SW_br = G @ soaw_w_br + PESO_br  (both branches, z=16) ----
  {
    GArgs a = {};
    a.W[0] = SOW0; a.W[1] = SOW1;
    a.X[0] = G; a.X[1] = G;
    a.out[0] = SW; a.out[1] = SW + (size_t)NB * NQ * 128;
    a.res[0] = PESO0; a.res[1] = PESO1;
    a.rscale[0] = 1.f; a.rscale[1] = 1.f;
    a.K = 256; a.ldm = 128; a.bmask = 7; a.brshift = 3;
    gemm_bf16<2><<<dim3(32, 1, 16), blk, 0, stream>>>(a);
  }

  // ---- VP_br = X_br @ WV_br + BV_br (combined conv+proj, both branches) ----
  {
    GArgs a = {};
    a.W[0] = WV0; a.W[1] = WV1;
    a.X[0] = XS; a.X[1] = XO;
    a.bias[0] = BV0; a.bias[1] = BV1;
    a.out[0] = VP0b; a.out[1] = VP1b;
    a.K = 320; a.ldm = 256; a.bmask = 7; a.brshift = 3;
    gemm_bf16<0><<<dim3(32, 2, 16), blk, 0, stream>>>(a);
  }

  // ---- sampling (both branches) ----
  k_sample<<<dim3(512, 16), blk, 0, stream>>>(VP0b, VP1b, SW, OATT0, OATT1);

  // ---- output proj br0 -> SATO ----
  {
    GArgs a = {};
    a.W[0] = OPT0; a.W[1] = OPT0;
    a.X[0] = OATT0; a.X[1] = OATT0;
    a.bias[0] = op_b[0]; a.bias[1] = op_b[0];
    a.out[0] = SATO; a.out[1] = SATO;
    a.rscale[0] = 2.f; a.rscale[1] = 2.f;
    a.G = G; a.PET = PET;
    a.K = 256; a.ldm = 256; a.bmask = 7; a.brshift = 31;
    gemm_bf16<3><<<dim3(32, 2, NB), blk, 0, stream>>>(a);
  }
  // ---- output proj br1 + blend -> FUSED ----
  {
    GArgs a = {};
    a.W[0] = OPT1; a.W[1] = OPT1;
    a.X[0] = OATT1; a.X[1] = OATT1;
    a.bias[0] = op_b[1]; a.bias[1] = op_b[1];
    a.out[0] = FUSED; a.out[1] = FUSED;
    a.rscale[0] = 4.f; a.rscale[1] = 4.f;
    a.G = G; a.PET = PET;
    a.other = SATO; a.afin = AFIN;
    a.K = 256; a.ldm = 256; a.bmask = 7; a.brshift = 31;
    gemm_bf16<4><<<dim3(32, 2, NB), blk, 0, stream>>>(a);
  }
  // ---- up conv -> f32 out ----
  {
    GArgs a = {};
    a.W[0] = WUP; a.W[1] = WUP;
    a.X[0] = FUSED; a.X[1] = FUSED;
    a.bias[0] = BUPP; a.bias[1] = BUPP;
    a.out[0] = out32; a.out[1] = out32;
    a.K = 256; a.ldm = 0; a.Mreal = 320; a.bmask = 7; a.brshift = 31;
    gemm_bf16<5><<<dim3(32, 3, NB), blk, 0, stream>>>(a);
  }
}